// Round 1
// baseline (2880.885 us; speedup 1.0000x reference)
//
#include <hip/hip_runtime.h>
#include <math.h>

#define NTOKEN 15000
#define EMBED  1024
#define HID    1024
#define VDIM   2048
#define MAXLEN 20
#define BATCH  128
#define NOBJ   36
#define TSTEP  19

typedef unsigned short ushort_t;
typedef __attribute__((ext_vector_type(8))) short short8;
typedef __attribute__((ext_vector_type(4))) float floatx4;

__device__ __forceinline__ float b2f(ushort_t u) {
    return __uint_as_float(((unsigned)u) << 16);
}
__device__ __forceinline__ ushort_t f2b(float f) {
    unsigned x = __float_as_uint(f);
    unsigned r = (x + 0x7fffu + ((x >> 16) & 1u)) >> 16;
    return (ushort_t)r;
}

// ---------------------------------------------------------------------------
// MFMA bf16 GEMM core: C[crow?[m]][n] = post( A[arow?[m]][k0:k0+K] @ B^T )
//   post: +bias[n], +cadd[(m/cadd_div)*ldadd+n], relu if n<relu_n, *mulvec[n]
// A: [M x ?] bf16(ushort) row-major (lda); B: [N x ?] bf16 row-major (ldb).
// BM = 128 (M % 128 == 0), BN = NF*16, K % 32 == 0. N guarded.
// LDS padded to stride 40 (80 B) -> conflict-free ds_read_b128.
// B staging stages exactly NF*16 rows (NF=2 used to waste half).
// ---------------------------------------------------------------------------
template<int NF, bool OUT_BF16>
__device__ __forceinline__ void mfma_core(
    ushort_t* As, ushort_t* Bs,
    const ushort_t* __restrict__ A, int lda, const int* __restrict__ arow,
    const ushort_t* __restrict__ B, int ldb,
    void* __restrict__ Cv, int ldc, const int* __restrict__ crow,
    const float* __restrict__ bias, const float* __restrict__ mulvec,
    const float* __restrict__ cadd, long ldadd, int cadd_div,
    int relu_n, int N, int K, int m0, int n0, int k0)
{
    const int tid  = threadIdx.x;
    const int lane = tid & 63;
    const int w    = tid >> 6;

    floatx4 acc[2][NF];
#pragma unroll
    for (int mf = 0; mf < 2; mf++)
#pragma unroll
        for (int nf = 0; nf < NF; nf++) acc[mf][nf] = (floatx4){0.f, 0.f, 0.f, 0.f};

    // staging assignment
    const int a_r = tid >> 1;          // 128 rows, 2 threads/row
    const int a_c = (tid & 1) * 16;    // each thread: cols a_c..a_c+15 (2 x 16B)
    const int b_r = (NF == 4) ? (tid >> 2) : (tid >> 3);   // NF*16 rows
    const int b_c = (NF == 4) ? ((tid & 3) * 8) : ((tid & 7) * 4);
    int a_g = m0 + a_r;
    if (arow) a_g = arow[a_g];
    int b_g = n0 + b_r;
    if (b_g >= N) b_g = N - 1;
    const ushort_t* Aptr = A + (long)a_g * lda + k0 + a_c;
    const ushort_t* Bptr = B + (long)b_g * ldb + k0 + b_c;

    uint4 av0 = *(const uint4*)(Aptr);
    uint4 av1 = *(const uint4*)(Aptr + 8);
    uint4 bv;
    if constexpr (NF == 4) bv = *(const uint4*)(Bptr);
    else { uint2 t2 = *(const uint2*)(Bptr); bv.x = t2.x; bv.y = t2.y; }

    const int fr = lane & 15;
    const int q8 = (lane >> 4) * 8;

    for (int kk = 0; kk < K; kk += 32) {
        __syncthreads();
        *(uint4*)(As + a_r * 40 + a_c)     = av0;
        *(uint4*)(As + a_r * 40 + a_c + 8) = av1;
        if constexpr (NF == 4) *(uint4*)(Bs + b_r * 40 + b_c) = bv;
        else                   *(uint2*)(Bs + b_r * 40 + b_c) = make_uint2(bv.x, bv.y);
        if (kk + 32 < K) {
            av0 = *(const uint4*)(Aptr + kk + 32);
            av1 = *(const uint4*)(Aptr + kk + 40);
            if constexpr (NF == 4) bv = *(const uint4*)(Bptr + kk + 32);
            else { uint2 t2 = *(const uint2*)(Bptr + kk + 32); bv.x = t2.x; bv.y = t2.y; }
        }
        __syncthreads();
        short8 bfrag[NF];
#pragma unroll
        for (int nf = 0; nf < NF; nf++)
            bfrag[nf] = *(const short8*)(Bs + (nf * 16 + fr) * 40 + q8);
#pragma unroll
        for (int mf = 0; mf < 2; mf++) {
            short8 afrag = *(const short8*)(As + (w * 32 + mf * 16 + fr) * 40 + q8);
#pragma unroll
            for (int nf = 0; nf < NF; nf++)
                acc[mf][nf] = __builtin_amdgcn_mfma_f32_16x16x32_bf16(
                    afrag, bfrag[nf], acc[mf][nf], 0, 0, 0);
        }
    }

    const int rq = lane >> 4;
#pragma unroll
    for (int mf = 0; mf < 2; mf++) {
#pragma unroll
        for (int r = 0; r < 4; r++) {
            int m = m0 + w * 32 + mf * 16 + rq * 4 + r;
            int cm = crow ? crow[m] : m;
            const float* caddrow = cadd ? (cadd + (long)(m / cadd_div) * ldadd) : nullptr;
#pragma unroll
            for (int nf = 0; nf < NF; nf++) {
                int n = n0 + nf * 16 + fr;
                if (n < N) {
                    float val = acc[mf][nf][r];
                    if (bias)    val += bias[n];
                    if (caddrow) val += caddrow[n];
                    if (n < relu_n) val = fmaxf(val, 0.f);
                    if (mulvec)  val *= mulvec[n];
                    if (OUT_BF16) ((ushort_t*)Cv)[(long)cm * ldc + n] = f2b(val);
                    else          ((float*)Cv)[(long)cm * ldc + n]   = val;
                }
            }
        }
    }
}

template<int NF, bool OUT_BF16>
__global__ __launch_bounds__(256) void mfma_gemm(
    const ushort_t* __restrict__ A, int lda, const int* __restrict__ arow,
    const ushort_t* __restrict__ B, int ldb,
    void* __restrict__ C, int ldc, const int* __restrict__ crow,
    const float* __restrict__ bias, const float* __restrict__ mulvec,
    const float* __restrict__ cadd, long ldadd, int cadd_div,
    int relu_n, int N, int K)
{
    __shared__ ushort_t As[128 * 40];
    __shared__ ushort_t Bs[64 * 40];
    mfma_core<NF, OUT_BF16>(As, Bs, A, lda, arow, B, ldb, C, ldc, crow,
                            bias, mulvec, cadd, ldadd, cadd_div, relu_n,
                            N, K, blockIdx.y * 128, blockIdx.x * (NF * 16), 0);
}

// split-K GEMM: blockIdx.y = split s; split 0 -> C0 (+bias/cadd), s>0 -> CP[s-1]
template<int NF, int KS>
__global__ __launch_bounds__(256) void splitk_gemm(
    const ushort_t* __restrict__ A, int lda,
    const ushort_t* __restrict__ B, int ldb,
    float* __restrict__ C0, float* __restrict__ CP, long pstride, int ldc,
    const float* __restrict__ bias,
    const float* __restrict__ cadd, long ldadd,
    int N, int K)
{
    __shared__ ushort_t As[128 * 40];
    __shared__ ushort_t Bs[64 * 40];
    const int s = blockIdx.y;
    const int Kc = K / KS;
    float* C = (s == 0) ? C0 : (CP + (long)(s - 1) * pstride);
    mfma_core<NF, false>(As, Bs, A, lda, nullptr, B, ldb, C, ldc, nullptr,
                         s == 0 ? bias : nullptr, nullptr,
                         s == 0 ? cadd : nullptr, ldadd, 1,
                         0, N, Kc, 0, blockIdx.x * (NF * 16), s * Kc);
}

// fused per-step GEMM trio with split-K: z=0 gi1, z=1 gh1, z=2 gh2
template<int NF, int KS>
__global__ __launch_bounds__(256) void step3_kernel(
    const ushort_t* __restrict__ h1b, const ushort_t* __restrict__ h2b,
    const ushort_t* __restrict__ Wih1h, const ushort_t* __restrict__ Whh1b,
    const ushort_t* __restrict__ Whh2b,
    float* __restrict__ gi, float* __restrict__ gh, float* __restrict__ gh2,
    float* __restrict__ P_gi, float* __restrict__ P_gh, float* __restrict__ P_gh2,
    const float* __restrict__ gi1s_t,
    const float* __restrict__ bhh1, const float* __restrict__ bhh2)
{
    __shared__ ushort_t As[128 * 40];
    __shared__ ushort_t Bs[64 * 40];
    const int s = blockIdx.y;
    const int Kc = 1024 / KS;
    const ushort_t* A; const ushort_t* B; float* C0; float* CP;
    const float* bias = nullptr; const float* cadd = nullptr;
    if (blockIdx.z == 0)      { A = h2b; B = Wih1h; C0 = gi;  CP = P_gi;  cadd = gi1s_t; }
    else if (blockIdx.z == 1) { A = h1b; B = Whh1b; C0 = gh;  CP = P_gh;  bias = bhh1; }
    else                      { A = h2b; B = Whh2b; C0 = gh2; CP = P_gh2; bias = bhh2; }
    float* C = (s == 0) ? C0 : (CP + (long)(s - 1) * 393216);
    mfma_core<NF, false>(As, Bs, A, 1024, nullptr, B, 1024, C, 3072, nullptr,
                         s == 0 ? bias : nullptr, nullptr,
                         s == 0 ? cadd : nullptr, (long)TSTEP * 3072, 1, 0,
                         3072, Kc, 0, blockIdx.x * (NF * 16), s * Kc);
}

// ---------------------------------------------------------------------------
// small helper kernels
// ---------------------------------------------------------------------------
__global__ void init_kernel(const int* __restrict__ caption,
                            int* __restrict__ tok_idx, int* __restrict__ crow20,
                            float* __restrict__ h12f, ushort_t* __restrict__ h12b)
{
    int idx = blockIdx.x * 256 + threadIdx.x;   // 262144 threads
    if (idx < BATCH * TSTEP) {
        int b = idx / TSTEP, t = idx % TSTEP;
        tok_idx[idx] = caption[b * MAXLEN + t];
        crow20[idx]  = b * MAXLEN + t;
    }
    h12f[idx] = 0.f;
    h12b[idx] = 0;
}

__global__ void sort_caption_kernel(const int* __restrict__ caption,
                                    const int* __restrict__ cap_len,
                                    float* __restrict__ out1)
{
    int i = threadIdx.x;
    if (i < BATCH) {
        int li = cap_len[i];
        int rank = 0;
        for (int j = 0; j < BATCH; j++) {
            int lj = cap_len[j];
            if (lj > li || (lj == li && j < i)) rank++;
        }
        for (int k = 0; k < TSTEP; k++)
            out1[rank * TSTEP + k] = (float)caption[i * MAXLEN + 1 + k];
    }
}

__global__ void vmean_kernel(const float* __restrict__ v,
                             float* __restrict__ vmean, ushort_t* __restrict__ vmeanb)
{
    int idx = blockIdx.x * 256 + threadIdx.x;   // BATCH*VDIM
    int b = idx >> 11, d = idx & (VDIM - 1);
    float s = 0.f;
    for (int o = 0; o < NOBJ; o++) s += v[((long)b * NOBJ + o) * VDIM + d];
    float m = s * (1.0f / 36.0f);
    vmean[idx] = m;
    vmeanb[idx] = f2b(m);
}

// strided (optionally row-gathered) f32 -> bf16 convert, 4 elems/thread
__global__ void conv_kernel(const float* __restrict__ src, long ld,
                            const int* __restrict__ rowidx,
                            ushort_t* __restrict__ dst, int rows, int cols)
{
    long idx4 = ((long)blockIdx.x * 256 + threadIdx.x) * 4;
    if (idx4 >= (long)rows * cols) return;
    int r = (int)(idx4 / cols);
    int c = (int)(idx4 % cols);
    long sr = rowidx ? rowidx[r] : r;
    float4 f = *(const float4*)(src + sr * ld + c);
    dst[idx4 + 0] = f2b(f.x);
    dst[idx4 + 1] = f2b(f.y);
    dst[idx4 + 2] = f2b(f.z);
    dst[idx4 + 3] = f2b(f.w);
}

// Wfc1 [1024x1024] -> Wfc1T bf16 (dst[n*1024+k] = src[k*1024+n])
__global__ void transpose_conv_kernel(const float* __restrict__ src,
                                      ushort_t* __restrict__ dst)
{
    __shared__ float tile[32][33];
    int bx = blockIdx.x, by = blockIdx.y;
    int lx = threadIdx.x & 31, ly = threadIdx.x >> 5;   // ly 0..7
    for (int i = 0; i < 32; i += 8)
        tile[ly + i][lx] = src[(long)(by * 32 + ly + i) * 1024 + bx * 32 + lx];
    __syncthreads();
    for (int i = 0; i < 32; i += 8)
        dst[(long)(bx * 32 + ly + i) * 1024 + by * 32 + lx] = f2b(tile[lx][ly + i]);
}

// bcat2[0:1024] = bq + Wq @ bfc1 ; bcat2[1024:4096] = bih2 + Wih2[:,2048:] @ bfc1
__global__ void bias_fold_kernel(const float* __restrict__ Wq,
                                 const float* __restrict__ Wih2,
                                 const float* __restrict__ bfc1,
                                 const float* __restrict__ bq,
                                 const float* __restrict__ bih2,
                                 float* __restrict__ bcat2)
{
    int wave = blockIdx.x * 4 + (threadIdx.x >> 6);
    int lane = threadIdx.x & 63;
    for (int n = wave; n < 4096; n += 256) {
        const float* wrow = (n < 1024) ? (Wq + (long)n * 1024)
                                       : (Wih2 + (long)(n - 1024) * 3072 + 2048);
        float s = 0.f;
        for (int j = lane; j < 1024; j += 64) s += wrow[j] * bfc1[j];
        for (int off = 32; off > 0; off >>= 1) s += __shfl_down(s, off);
        if (lane == 0) bcat2[n] = s + ((n < 1024) ? bq[n] : bih2[n - 1024]);
    }
}

// GRU combine with split-K partial reduction:
//   gate = gi[..] + sum_s giP[s][..] ;  same for gh
__global__ void gru_kernel(const float* __restrict__ gi, const float* __restrict__ giP,
                           const float* __restrict__ gh, const float* __restrict__ ghP,
                           int nsp,
                           float* __restrict__ h, ushort_t* __restrict__ hb,
                           ushort_t* __restrict__ hstore, int t)
{
    int idx = blockIdx.x * 256 + threadIdx.x;   // BATCH*HID
    int b = idx >> 10, j = idx & (HID - 1);
    long o0 = (long)b * 3 * HID + j;
    float ir = gi[o0], iz = gi[o0 + HID], in_ = gi[o0 + 2 * HID];
    float hr = gh[o0], hz = gh[o0 + HID], hn  = gh[o0 + 2 * HID];
    for (int s = 0; s < nsp; s++) {
        const float* gp = giP + (long)s * 393216;
        const float* hp = ghP + (long)s * 393216;
        ir  += gp[o0]; iz += gp[o0 + HID]; in_ += gp[o0 + 2 * HID];
        hr  += hp[o0]; hz += hp[o0 + HID]; hn  += hp[o0 + 2 * HID];
    }
    float r = 1.f / (1.f + expf(-(ir + hr)));
    float z = 1.f / (1.f + expf(-(iz + hz)));
    float n = tanhf(in_ + r * hn);
    float hnew = (1.f - z) * n + z * h[idx];
    h[idx] = hnew;
    ushort_t hq = f2b(hnew);
    hb[idx] = hq;
    if (hstore) hstore[((long)(b * TSTEP + t) << 10) | j] = hq;
}

// attention: sum qgi2 partials (relu on q part), logits -> softmax(36) -> alpha,
// att_v(bf16); also emits qh_sum[b][0:3072] = summed gi2_h for the gi2 GEMM cadd.
__global__ __launch_bounds__(256) void attention_kernel(
    const ushort_t* __restrict__ vwb, const float* __restrict__ qgi2,
    const float* __restrict__ qP,
    const float* __restrict__ v, const int* __restrict__ cap_len, int t,
    ushort_t* __restrict__ x2v, float* __restrict__ alpha,
    float* __restrict__ qh_sum)
{
    int b = blockIdx.x;
    __shared__ float qs[HID];
    __shared__ float att_s[NOBJ];
    int tid = threadIdx.x;
    int lane = tid & 63, w = tid >> 6;
    const float* qb = qgi2 + (long)b * 4096;

    // q = relu(sum of 4 partials) into LDS
    for (int hh = tid; hh < HID; hh += 256) {
        float s = qb[hh];
        for (int sp = 0; sp < 3; sp++) s += qP[(long)sp * 524288 + (long)b * 4096 + hh];
        qs[hh] = fmaxf(s, 0.f);
    }
    // gi2_h summed (no relu) for the gi2 GEMM
    for (int jj = tid; jj < 3072; jj += 256) {
        float s = qb[HID + jj];
        for (int sp = 0; sp < 3; sp++)
            s += qP[(long)sp * 524288 + (long)b * 4096 + HID + jj];
        qh_sum[(long)b * 3072 + jj] = s;
    }
    __syncthreads();

    for (int o = w; o < NOBJ; o += 4) {
        const ushort_t* vwo = vwb + ((long)b * NOBJ + o) * HID;
        float s = 0.f;
        for (int hh = lane; hh < HID; hh += 64) s += b2f(vwo[hh]) * qs[hh];
        for (int off = 32; off > 0; off >>= 1) s += __shfl_down(s, off);
        if (lane == 0) att_s[o] = s;
    }
    __syncthreads();
    if (tid == 0) {
        float mx = att_s[0];
        for (int o = 1; o < NOBJ; o++) mx = fmaxf(mx, att_s[o]);
        float sum = 0.f;
        for (int o = 0; o < NOBJ; o++) { float e = expf(att_s[o] - mx); att_s[o] = e; sum += e; }
        float inv = 1.f / sum;
        for (int o = 0; o < NOBJ; o++) att_s[o] *= inv;
    }
    __syncthreads();
    bool m = (t < cap_len[b] - 1);
    if (tid < NOBJ) alpha[((long)b * MAXLEN + t) * NOBJ + tid] = m ? att_s[tid] : 0.f;
    for (int d = tid; d < VDIM; d += 256) {
        float s = 0.f;
        for (int o = 0; o < NOBJ; o++) s += att_s[o] * v[((long)b * NOBJ + o) * VDIM + d];
        x2v[(long)b * VDIM + d] = f2b(s);
    }
}

// row softmax over NTOKEN; masked rows -> uniform; t==19 alpha rows -> 0
__global__ __launch_bounds__(256) void softmax_kernel(float* __restrict__ predict,
                                                      float* __restrict__ alpha,
                                                      const int* __restrict__ cap_len)
{
    __shared__ float sred[4];
    int row = blockIdx.x;                 // b*20 + t
    int b = row / MAXLEN, t = row % MAXLEN;
    float* p = predict + (long)row * NTOKEN;
    int tid = threadIdx.x;
    int dec = cap_len[b] - 1;
    if (t >= dec) {
        const float u = 1.0f / (float)NTOKEN;
        for (int i = tid; i < NTOKEN; i += 256) p[i] = u;
        if (t == MAXLEN - 1 && tid < NOBJ) alpha[(long)row * NOBJ + tid] = 0.f;
        return;
    }
    float mx = -3.4e38f;
    for (int i = tid; i < NTOKEN; i += 256) mx = fmaxf(mx, p[i]);
    for (int off = 32; off > 0; off >>= 1) mx = fmaxf(mx, __shfl_down(mx, off));
    if ((tid & 63) == 0) sred[tid >> 6] = mx;
    __syncthreads();
    mx = fmaxf(fmaxf(sred[0], sred[1]), fmaxf(sred[2], sred[3]));
    __syncthreads();
    float s = 0.f;
    for (int i = tid; i < NTOKEN; i += 256) s += expf(p[i] - mx);
    for (int off = 32; off > 0; off >>= 1) s += __shfl_down(s, off);
    if ((tid & 63) == 0) sred[tid >> 6] = s;
    __syncthreads();
    s = sred[0] + sred[1] + sred[2] + sred[3];
    float inv = 1.f / s;
    for (int i = tid; i < NTOKEN; i += 256) p[i] = expf(p[i] - mx) * inv;
}

// ---------------------------------------------------------------------------
extern "C" void kernel_launch(void* const* d_in, const int* in_sizes, int n_in,
                              void* d_out, int out_size, void* d_ws, size_t ws_size,
                              hipStream_t stream)
{
    const float* v       = (const float*)d_in[0];
    const int*   caption = (const int*)  d_in[1];
    const int*   cap_len = (const int*)  d_in[2];
    const float* emb     = (const float*)d_in[3];
    const float* Wih1    = (const float*)d_in[4];
    const float* Whh1    = (const float*)d_in[5];
    const float* bih1    = (const float*)d_in[6];
    const float* bhh1    = (const float*)d_in[7];
    const float* Wih2    = (const float*)d_in[8];
    const float* Whh2    = (const float*)d_in[9];
    const float* bih2    = (const float*)d_in[10];
    const float* bhh2    = (const float*)d_in[11];
    const float* Wfc1    = (const float*)d_in[12];
    const float* bfc1    = (const float*)d_in[13];
    const float* Wfc2    = (const float*)d_in[14];
    const float* bfc2    = (const float*)d_in[15];
    const float* Wv      = (const float*)d_in[16];
    const float* bv      = (const float*)d_in[17];
    const float* Wq      = (const float*)d_in[18];
    const float* bq      = (const float*)d_in[19];
    const float* Wa      = (const float*)d_in[20];
    // ba cancels in softmax

    // ---- workspace layout ----
    float* f32base = (float*)d_ws;
    float* gvm   = f32base;              // 128*3072
    float* gi1s  = gvm   + 393216;       // 2432*3072
    float* h1    = gi1s  + 7471104;      // 128*1024  (h1,h2 contiguous)
    float* h2    = h1    + 131072;
    float* gi    = h2    + 131072;       // 128*3072
    float* gh    = gi    + 393216;
    float* gh2   = gh    + 393216;
    float* qgi2  = gh2   + 393216;       // 128*4096
    float* vmean = qgi2  + 524288;       // 128*2048
    float* bcat2 = vmean + 262144;       // 4096
    ushort_t* ub = (ushort_t*)(bcat2 + 4096);
    ushort_t* Wih1h = ub;                 // 3072*1024
    ushort_t* Wih1c = Wih1h + 3145728;    // 3072*1024
    ushort_t* Whh1b = Wih1c + 3145728;    // 3072*1024
    ushort_t* Whh2b = Whh1b + 3145728;    // 3072*1024
    ushort_t* Wih2v = Whh2b + 3145728;    // 3072*2048
    ushort_t* Wcat2 = Wih2v + 6291456;    // 4096*1024
    ushort_t* Wfc2b = Wcat2 + 4194304;    // 15000*1024
    ushort_t* vw_bf = Wfc2b + 15360000;   // 4608*1024
    ushort_t* H2Ab  = vw_bf + 4718592;    // 2432*1024
    ushort_t* h1b   = H2Ab  + 2490368;    // 128*1024 (h1b,h2b contiguous)
    ushort_t* h2b   = h1b   + 131072;
    ushort_t* x2v   = h2b   + 131072;     // 128*2048
    ushort_t* vmeanb= x2v   + 262144;     // 128*2048
    ushort_t* TEMP  = vmeanb+ 262144;     // 11534336 max
    // TEMP sub-uses — prologue scratch (sequential in stream):
    ushort_t* vb     = TEMP;              // 4608*2048
    ushort_t* Wvb    = TEMP + 9437184;    // 1024*2048
    ushort_t* Wqb    = TEMP;              // 1024*1024
    ushort_t* Wih2hb = TEMP + 1048576;    // 3072*1024
    ushort_t* Wfc1T  = TEMP + 4194304;    // 1024*1024
    ushort_t* Wih1m  = TEMP;              // 3072*2048
    ushort_t* Acap   = TEMP;              // 2432*1024
    // TEMP sub-uses — recurrent-loop split-K partials (TEMP is dead in the loop):
    float* TEMPf  = (float*)TEMP;         // 5767168 floats capacity
    float* P_gi   = TEMPf;                // 3 * 393216
    float* P_gh   = P_gi  + 3 * 393216;   // 3 * 393216
    float* P_gh2  = P_gh  + 3 * 393216;   // 3 * 393216
    float* P_q    = P_gh2 + 3 * 393216;   // 3 * 524288
    float* qh_sum = P_q   + 3 * 524288;   // 393216   (total 5505024 < 5767168)
    int* tok_idx = (int*)(TEMP + 11534336);
    int* crow20  = tok_idx + BATCH * TSTEP;

    float* out     = (float*)d_out;
    float* predict = out;                                   // 128*20*15000
    float* out1    = out + (long)BATCH * MAXLEN * NTOKEN;   // 128*19
    float* alpha   = out1 + (long)BATCH * TSTEP;            // 128*20*36

    #define CONV(src, ld, rowidx, dst, rows, cols) \
        conv_kernel<<<(int)(((long)(rows)*(cols)/4 + 255)/256), 256, 0, stream>>>( \
            src, ld, rowidx, dst, rows, cols)

    // ---- prologue ----
    init_kernel<<<1024, 256, 0, stream>>>(caption, tok_idx, crow20, h1, h1b);
    sort_caption_kernel<<<1, 128, 0, stream>>>(caption, cap_len, out1);
    vmean_kernel<<<(BATCH * VDIM) / 256, 256, 0, stream>>>(v, vmean, vmeanb);

    CONV(Wih1,        4096, nullptr, Wih1h, 3072, 1024);
    CONV(Wih1 + 3072, 4096, nullptr, Wih1c, 3072, 1024);
    CONV(Whh1,        1024, nullptr, Whh1b, 3072, 1024);
    CONV(Whh2,        1024, nullptr, Whh2b, 3072, 1024);
    CONV(Wih2,        3072, nullptr, Wih2v, 3072, 2048);
    CONV(Wfc2,        1024, nullptr, Wfc2b, NTOKEN, 1024);

    // vw = relu(v @ Wv^T + bv) * Wa  -> bf16 [4608 x 1024]
    CONV(v,  2048, nullptr, vb,  4608, 2048);
    CONV(Wv, 2048, nullptr, Wvb, 1024, 2048);
    mfma_gemm<4, true><<<dim3(16, 36), 256, 0, stream>>>(
        vb, 2048, nullptr, Wvb, 2048, vw_bf, 1024, nullptr,
        bv, Wa, nullptr, 0, 1, 1024, 1024, 2048);

    // folded weights: Wcat2 = [Wq@Wfc1 ; Wih2[:,2048:]@Wfc1]
    CONV(Wq,          1024, nullptr, Wqb,    1024, 1024);
    CONV(Wih2 + 2048, 3072, nullptr, Wih2hb, 3072, 1024);
    transpose_conv_kernel<<<dim3(32, 32), 256, 0, stream>>>(Wfc1, Wfc1T);
    mfma_gemm<4, true><<<dim3(16, 8), 256, 0, stream>>>(
        Wqb, 1024, nullptr, Wfc1T, 1024, Wcat2, 1024, nullptr,
        nullptr, nullptr, nullptr, 0, 1, 0, 1024, 1024);
    mfma_gemm<4, true><<<dim3(16, 24), 256, 0, stream>>>(
        Wih2hb, 1024, nullptr, Wfc1T, 1024, Wcat2 + 1048576, 1024, nullptr,
        nullptr, nullptr, nullptr, 0, 1, 0, 1024, 1024);
    bias_fold_kernel<<<64, 256, 0, stream>>>(Wq, Wih2, bfc1, bq, bih2, bcat2);

    // gvm = vmean @ Wih1[:,1024:3072]^T + bih1  (f32 [128 x 3072])
    CONV(Wih1 + 1024, 4096, nullptr, Wih1m, 3072, 2048);
    mfma_gemm<4, false><<<dim3(48, 1), 256, 0, stream>>>(
        vmeanb, 2048, nullptr, Wih1m, 2048, gvm, 3072, nullptr,
        bih1, nullptr, nullptr, 0, 1, 0, 3072, 2048);

    // gi1s[b*19+t] = emb[cap[b,t]] @ Wih1[:,3072:]^T + gvm[b]
    CONV(emb, 1024, tok_idx, Acap, 2432, 1024);
    mfma_gemm<4, false><<<dim3(48, 19), 256, 0, stream>>>(
        Acap, 1024, nullptr, Wih1c, 1024, gi1s, 3072, nullptr,
        nullptr, nullptr, gvm, 3072, TSTEP, 0, 3072, 1024);

    // ---- recurrent loop (split-K x4 on all GEMMs; partials in TEMP) ----
    for (int t = 0; t < TSTEP; t++) {
        step3_kernel<2, 4><<<dim3(96, 4, 3), 256, 0, stream>>>(
            h1b, h2b, Wih1h, Whh1b, Whh2b, gi, gh, gh2,
            P_gi, P_gh, P_gh2, gi1s + (long)t * 3072, bhh1, bhh2);
        gru_kernel<<<512, 256, 0, stream>>>(gi, P_gi, gh, P_gh, 3, h1, h1b, nullptr, t);
        // [q | gi2_h] = h1' @ Wcat2^T + bcat2 (relu deferred to attention)
        splitk_gemm<2, 4><<<dim3(128, 4), 256, 0, stream>>>(
            h1b, 1024, Wcat2, 1024, qgi2, P_q, 524288, 4096,
            bcat2, nullptr, 0, 4096, 1024);
        attention_kernel<<<BATCH, 256, 0, stream>>>(
            vw_bf, qgi2, P_q, v, cap_len, t, x2v, alpha, qh_sum);
        // gi2 = att_v @ Wih2[:, :2048]^T + qh_sum
        splitk_gemm<2, 4><<<dim3(96, 4), 256, 0, stream>>>(
            x2v, 2048, Wih2v, 2048, gi, P_gi, 393216, 3072,
            nullptr, qh_sum, 3072, 3072, 2048);
        gru_kernel<<<512, 256, 0, stream>>>(gi, P_gi, gh2, P_gh2, 3, h2, h2b, H2Ab, t);
    }

    // ---- epilogue ----
    mfma_gemm<4, false><<<dim3(235, 19), 256, 0, stream>>>(
        H2Ab, 1024, nullptr, Wfc2b, 1024, predict, NTOKEN, crow20,
        bfc2, nullptr, nullptr, 0, 1, 0, NTOKEN, 1024);
    softmax_kernel<<<BATCH * MAXLEN, 256, 0, stream>>>(predict, alpha, cap_len);
    #undef CONV
}

// Round 4
// 2356.741 us; speedup vs baseline: 1.2224x; 1.2224x over previous
//
#include <hip/hip_runtime.h>
#include <math.h>

#define NTOKEN 15000
#define EMBED  1024
#define HID    1024
#define VDIM   2048
#define MAXLEN 20
#define BATCH  128
#define NOBJ   36
#define TSTEP  19

typedef unsigned short ushort_t;
typedef __attribute__((ext_vector_type(8))) short short8;
typedef __attribute__((ext_vector_type(4))) float floatx4;

__device__ __forceinline__ float b2f(ushort_t u) {
    return __uint_as_float(((unsigned)u) << 16);
}
__device__ __forceinline__ ushort_t f2b(float f) {
    unsigned x = __float_as_uint(f);
    unsigned r = (x + 0x7fffu + ((x >> 16) & 1u)) >> 16;
    return (ushort_t)r;
}

// ---------------------------------------------------------------------------
// MFMA bf16 GEMM core, v2: LDS double-buffer, 1 barrier/k-iter, 2-deep global
// prefetch. C[crow?[m]][n] = post( A[arow?[m]][k0:k0+K] @ B^T )
// A: [M x ?] bf16 row-major (lda); B: [N x ?] bf16 row-major (ldb).
// BM = 128, BN = NF*16, K % 64 == 0 (T=K/32 even, >= 2). N guarded.
// LDS stride 40 ushorts (80 B); measured conflicts negligible.
// ---------------------------------------------------------------------------
template<int NF, bool OUT_BF16>
__device__ __forceinline__ void mfma_core(
    ushort_t* As, ushort_t* Bs,     // As[2][128*40], Bs[2][NF*16*40]
    const ushort_t* __restrict__ A, int lda, const int* __restrict__ arow,
    const ushort_t* __restrict__ B, int ldb,
    void* __restrict__ Cv, int ldc, const int* __restrict__ crow,
    const float* __restrict__ bias, const float* __restrict__ mulvec,
    const float* __restrict__ cadd, long ldadd, int cadd_div,
    int relu_n, int N, int K, int m0, int n0, int k0)
{
    constexpr int ABUF = 128 * 40;
    constexpr int BBUF = NF * 16 * 40;
    const int tid  = threadIdx.x;
    const int lane = tid & 63;
    const int w    = tid >> 6;

    floatx4 acc[2][NF];
#pragma unroll
    for (int mf = 0; mf < 2; mf++)
#pragma unroll
        for (int nf = 0; nf < NF; nf++) acc[mf][nf] = (floatx4){0.f, 0.f, 0.f, 0.f};

    // staging coords
    const int a_r = tid >> 1;
    const int a_c = (tid & 1) * 16;
    int a_g = m0 + a_r;
    if (arow) a_g = arow[a_g];
    const ushort_t* Aptr = A + (long)a_g * lda + k0 + a_c;

    int b_r, b_c;
    if constexpr (NF == 8)      { b_r = tid >> 1; b_c = (tid & 1) * 16; }
    else if constexpr (NF == 4) { b_r = tid >> 2; b_c = (tid & 3) * 8; }
    else                        { b_r = tid >> 3; b_c = (tid & 7) * 4; }
    int b_g = n0 + b_r;
    if (b_g >= N) b_g = N - 1;
    const ushort_t* Bptr = B + (long)b_g * ldb + k0 + b_c;

    const int fr = lane & 15;
    const int q8 = (lane >> 4) * 8;

    auto LDB = [&](uint4& v0, uint4& v1, int kof) {
        if constexpr (NF == 8) {
            v0 = *(const uint4*)(Bptr + kof);
            v1 = *(const uint4*)(Bptr + kof + 8);
        } else if constexpr (NF == 4) {
            v0 = *(const uint4*)(Bptr + kof);
        } else {
            uint2 t2 = *(const uint2*)(Bptr + kof);
            v0.x = t2.x; v0.y = t2.y;
        }
    };
    auto STA = [&](ushort_t* Asb, const uint4& v0, const uint4& v1) {
        *(uint4*)(Asb + a_r * 40 + a_c)     = v0;
        *(uint4*)(Asb + a_r * 40 + a_c + 8) = v1;
    };
    auto STB = [&](ushort_t* Bsb, const uint4& v0, const uint4& v1) {
        if constexpr (NF == 8) {
            *(uint4*)(Bsb + b_r * 40 + b_c)     = v0;
            *(uint4*)(Bsb + b_r * 40 + b_c + 8) = v1;
        } else if constexpr (NF == 4) {
            *(uint4*)(Bsb + b_r * 40 + b_c) = v0;
        } else {
            *(uint2*)(Bsb + b_r * 40 + b_c) = make_uint2(v0.x, v0.y);
        }
    };
    auto CMP = [&](const ushort_t* Asb, const ushort_t* Bsb) {
        short8 bfr[NF];
#pragma unroll
        for (int nf = 0; nf < NF; nf++)
            bfr[nf] = *(const short8*)(Bsb + (nf * 16 + fr) * 40 + q8);
#pragma unroll
        for (int mf = 0; mf < 2; mf++) {
            short8 af = *(const short8*)(Asb + (w * 32 + mf * 16 + fr) * 40 + q8);
#pragma unroll
            for (int nf = 0; nf < NF; nf++)
                acc[mf][nf] = __builtin_amdgcn_mfma_f32_16x16x32_bf16(
                    af, bfr[nf], acc[mf][nf], 0, 0, 0);
        }
    };

    const int T = K >> 5;   // even, >= 2

    uint4 ae0, ae1, ao0, ao1;
    uint4 be0, be1, bo0, bo1;
    // load iter 0 (even slot) + iter 1 (odd slot)
    ae0 = *(const uint4*)(Aptr);       ae1 = *(const uint4*)(Aptr + 8);
    LDB(be0, be1, 0);
    ao0 = *(const uint4*)(Aptr + 32);  ao1 = *(const uint4*)(Aptr + 40);
    LDB(bo0, bo1, 32);
    // stage iter 0 into buf0; issue loads for iter 2 into even slot
    STA(As, ae0, ae1); STB(Bs, be0, be1);
    if (T > 2) {
        ae0 = *(const uint4*)(Aptr + 64); ae1 = *(const uint4*)(Aptr + 72);
        LDB(be0, be1, 64);
    }
    __syncthreads();

    for (int i = 0; i < T; i += 2) {
        // even phase: compute buf0 (iter i); stage buf1 (iter i+1); load i+3 -> odd
        STA(As + ABUF, ao0, ao1); STB(Bs + BBUF, bo0, bo1);
        if (i + 3 < T) {
            int kof = (i + 3) * 32;
            ao0 = *(const uint4*)(Aptr + kof); ao1 = *(const uint4*)(Aptr + kof + 8);
            LDB(bo0, bo1, kof);
        }
        CMP(As, Bs);
        __syncthreads();
        // odd phase: compute buf1 (iter i+1); stage buf0 (iter i+2); load i+4 -> even
        if (i + 2 < T) {
            STA(As, ae0, ae1); STB(Bs, be0, be1);
            if (i + 4 < T) {
                int kof = (i + 4) * 32;
                ae0 = *(const uint4*)(Aptr + kof); ae1 = *(const uint4*)(Aptr + kof + 8);
                LDB(be0, be1, kof);
            }
        }
        CMP(As + ABUF, Bs + BBUF);
        __syncthreads();
    }

    const int rq = lane >> 4;
#pragma unroll
    for (int mf = 0; mf < 2; mf++) {
#pragma unroll
        for (int r = 0; r < 4; r++) {
            int m = m0 + w * 32 + mf * 16 + rq * 4 + r;
            int cm = crow ? crow[m] : m;
            const float* caddrow = cadd ? (cadd + (long)(m / cadd_div) * ldadd) : nullptr;
#pragma unroll
            for (int nf = 0; nf < NF; nf++) {
                int n = n0 + nf * 16 + fr;
                if (n < N) {
                    float val = acc[mf][nf][r];
                    if (bias)    val += bias[n];
                    if (caddrow) val += caddrow[n];
                    if (n < relu_n) val = fmaxf(val, 0.f);
                    if (mulvec)  val *= mulvec[n];
                    if (OUT_BF16) ((ushort_t*)Cv)[(long)cm * ldc + n] = f2b(val);
                    else          ((float*)Cv)[(long)cm * ldc + n]   = val;
                }
            }
        }
    }
}

// standalone GEMM; swz!=0 -> XCD-bijective n-slab swizzle (L2 locality)
template<int NF, bool OUT_BF16>
__global__ __launch_bounds__(256) void mfma_gemm(
    const ushort_t* __restrict__ A, int lda, const int* __restrict__ arow,
    const ushort_t* __restrict__ B, int ldb,
    void* __restrict__ C, int ldc, const int* __restrict__ crow,
    const float* __restrict__ bias, const float* __restrict__ mulvec,
    const float* __restrict__ cadd, long ldadd, int cadd_div,
    int relu_n, int N, int K, int swz)
{
    __shared__ ushort_t As[2 * 128 * 40];
    __shared__ ushort_t Bs[2 * NF * 16 * 40];
    int mt = blockIdx.y, nt = blockIdx.x;
    if (swz) {
        int D = gridDim.x * gridDim.y;
        int d = blockIdx.y * gridDim.x + blockIdx.x;   // dispatch-linear id
        int x = d & 7, j = d >> 3, q = D >> 3, r = D & 7;
        int g = x * q + (x < r ? x : r) + j;
        mt = g % gridDim.y; nt = g / gridDim.y;
    }
    mfma_core<NF, OUT_BF16>(As, Bs, A, lda, arow, B, ldb, C, ldc, crow,
                            bias, mulvec, cadd, ldadd, cadd_div, relu_n,
                            N, K, mt * 128, nt * (NF * 16), 0);
}

// split-K GEMM: blockIdx.y = split s; split 0 -> C0 (+bias/cadd), s>0 -> CP[s-1]
template<int NF, int KS>
__global__ __launch_bounds__(256) void splitk_gemm(
    const ushort_t* __restrict__ A, int lda,
    const ushort_t* __restrict__ B, int ldb,
    float* __restrict__ C0, float* __restrict__ CP, long pstride, int ldc,
    const float* __restrict__ bias,
    const float* __restrict__ cadd, long ldadd,
    int N, int K)
{
    __shared__ ushort_t As[2 * 128 * 40];
    __shared__ ushort_t Bs[2 * NF * 16 * 40];
    const int s = blockIdx.y;
    const int Kc = K / KS;
    float* C = (s == 0) ? C0 : (CP + (long)(s - 1) * pstride);
    mfma_core<NF, false>(As, Bs, A, lda, nullptr, B, ldb, C, ldc, nullptr,
                         s == 0 ? bias : nullptr, nullptr,
                         s == 0 ? cadd : nullptr, ldadd, 1,
                         0, N, Kc, 0, blockIdx.x * (NF * 16), s * Kc);
}

// fused per-step GEMM trio with split-K: z=0 gi1, z=1 gh1, z=2 gh2
template<int NF, int KS>
__global__ __launch_bounds__(256) void step3_kernel(
    const ushort_t* __restrict__ h1b, const ushort_t* __restrict__ h2b,
    const ushort_t* __restrict__ Wih1h, const ushort_t* __restrict__ Whh1b,
    const ushort_t* __restrict__ Whh2b,
    float* __restrict__ gi, float* __restrict__ gh, float* __restrict__ gh2,
    float* __restrict__ P_gi, float* __restrict__ P_gh, float* __restrict__ P_gh2,
    const float* __restrict__ gi1s_t,
    const float* __restrict__ bhh1, const float* __restrict__ bhh2)
{
    __shared__ ushort_t As[2 * 128 * 40];
    __shared__ ushort_t Bs[2 * NF * 16 * 40];
    const int s = blockIdx.y;
    const int Kc = 1024 / KS;
    const ushort_t* A; const ushort_t* B; float* C0; float* CP;
    const float* bias = nullptr; const float* cadd = nullptr;
    if (blockIdx.z == 0)      { A = h2b; B = Wih1h; C0 = gi;  CP = P_gi;  cadd = gi1s_t; }
    else if (blockIdx.z == 1) { A = h1b; B = Whh1b; C0 = gh;  CP = P_gh;  bias = bhh1; }
    else                      { A = h2b; B = Whh2b; C0 = gh2; CP = P_gh2; bias = bhh2; }
    float* C = (s == 0) ? C0 : (CP + (long)(s - 1) * 393216);
    mfma_core<NF, false>(As, Bs, A, 1024, nullptr, B, 1024, C, 3072, nullptr,
                         s == 0 ? bias : nullptr, nullptr,
                         s == 0 ? cadd : nullptr, (long)TSTEP * 3072, 1, 0,
                         3072, Kc, 0, blockIdx.x * (NF * 16), s * Kc);
}

// ---------------------------------------------------------------------------
// small helper kernels
// ---------------------------------------------------------------------------
__global__ void init_kernel(const int* __restrict__ caption,
                            int* __restrict__ tok_idx, int* __restrict__ crow20,
                            float* __restrict__ h12f, ushort_t* __restrict__ h12b)
{
    int idx = blockIdx.x * 256 + threadIdx.x;   // 262144 threads
    if (idx < BATCH * TSTEP) {
        int b = idx / TSTEP, t = idx % TSTEP;
        tok_idx[idx] = caption[b * MAXLEN + t];
        crow20[idx]  = b * MAXLEN + t;
    }
    h12f[idx] = 0.f;
    h12b[idx] = 0;
}

__global__ void sort_caption_kernel(const int* __restrict__ caption,
                                    const int* __restrict__ cap_len,
                                    float* __restrict__ out1)
{
    int i = threadIdx.x;
    if (i < BATCH) {
        int li = cap_len[i];
        int rank = 0;
        for (int j = 0; j < BATCH; j++) {
            int lj = cap_len[j];
            if (lj > li || (lj == li && j < i)) rank++;
        }
        for (int k = 0; k < TSTEP; k++)
            out1[rank * TSTEP + k] = (float)caption[i * MAXLEN + 1 + k];
    }
}

__global__ void vmean_kernel(const float* __restrict__ v,
                             float* __restrict__ vmean, ushort_t* __restrict__ vmeanb)
{
    int idx = blockIdx.x * 256 + threadIdx.x;   // BATCH*VDIM
    int b = idx >> 11, d = idx & (VDIM - 1);
    float s = 0.f;
    for (int o = 0; o < NOBJ; o++) s += v[((long)b * NOBJ + o) * VDIM + d];
    float m = s * (1.0f / 36.0f);
    vmean[idx] = m;
    vmeanb[idx] = f2b(m);
}

// strided (optionally row-gathered) f32 -> bf16 convert, 4 elems/thread
__global__ void conv_kernel(const float* __restrict__ src, long ld,
                            const int* __restrict__ rowidx,
                            ushort_t* __restrict__ dst, int rows, int cols)
{
    long idx4 = ((long)blockIdx.x * 256 + threadIdx.x) * 4;
    if (idx4 >= (long)rows * cols) return;
    int r = (int)(idx4 / cols);
    int c = (int)(idx4 % cols);
    long sr = rowidx ? rowidx[r] : r;
    float4 f = *(const float4*)(src + sr * ld + c);
    dst[idx4 + 0] = f2b(f.x);
    dst[idx4 + 1] = f2b(f.y);
    dst[idx4 + 2] = f2b(f.z);
    dst[idx4 + 3] = f2b(f.w);
}

// Wfc1 [1024x1024] -> Wfc1T bf16 (dst[n*1024+k] = src[k*1024+n])
__global__ void transpose_conv_kernel(const float* __restrict__ src,
                                      ushort_t* __restrict__ dst)
{
    __shared__ float tile[32][33];
    int bx = blockIdx.x, by = blockIdx.y;
    int lx = threadIdx.x & 31, ly = threadIdx.x >> 5;   // ly 0..7
    for (int i = 0; i < 32; i += 8)
        tile[ly + i][lx] = src[(long)(by * 32 + ly + i) * 1024 + bx * 32 + lx];
    __syncthreads();
    for (int i = 0; i < 32; i += 8)
        dst[(long)(bx * 32 + ly + i) * 1024 + by * 32 + lx] = f2b(tile[lx][ly + i]);
}

// bcat2[0:1024] = bq + Wq @ bfc1 ; bcat2[1024:4096] = bih2 + Wih2[:,2048:] @ bfc1
__global__ void bias_fold_kernel(const float* __restrict__ Wq,
                                 const float* __restrict__ Wih2,
                                 const float* __restrict__ bfc1,
                                 const float* __restrict__ bq,
                                 const float* __restrict__ bih2,
                                 float* __restrict__ bcat2)
{
    int wave = blockIdx.x * 4 + (threadIdx.x >> 6);
    int lane = threadIdx.x & 63;
    for (int n = wave; n < 4096; n += 256) {
        const float* wrow = (n < 1024) ? (Wq + (long)n * 1024)
                                       : (Wih2 + (long)(n - 1024) * 3072 + 2048);
        float s = 0.f;
        for (int j = lane; j < 1024; j += 64) s += wrow[j] * bfc1[j];
        for (int off = 32; off > 0; off >>= 1) s += __shfl_down(s, off);
        if (lane == 0) bcat2[n] = s + ((n < 1024) ? bq[n] : bih2[n - 1024]);
    }
}

// GRU combine (gru1): gate = gi + sum_s giP[s] ; same for gh
__global__ void gru_kernel(const float* __restrict__ gi, const float* __restrict__ giP,
                           const float* __restrict__ gh, const float* __restrict__ ghP,
                           int nsp,
                           float* __restrict__ h, ushort_t* __restrict__ hb,
                           ushort_t* __restrict__ hstore, int t)
{
    int idx = blockIdx.x * 256 + threadIdx.x;   // BATCH*HID
    int b = idx >> 10, j = idx & (HID - 1);
    long o0 = (long)b * 3 * HID + j;
    float ir = gi[o0], iz = gi[o0 + HID], in_ = gi[o0 + 2 * HID];
    float hr = gh[o0], hz = gh[o0 + HID], hn  = gh[o0 + 2 * HID];
    for (int s = 0; s < nsp; s++) {
        const float* gp = giP + (long)s * 393216;
        const float* hp = ghP + (long)s * 393216;
        ir  += gp[o0]; iz += gp[o0 + HID]; in_ += gp[o0 + 2 * HID];
        hr  += hp[o0]; hz += hp[o0 + HID]; hn  += hp[o0 + 2 * HID];
    }
    float r = 1.f / (1.f + expf(-(ir + hr)));
    float z = 1.f / (1.f + expf(-(iz + hz)));
    float n = tanhf(in_ + r * hn);
    float hnew = (1.f - z) * n + z * h[idx];
    h[idx] = hnew;
    ushort_t hq = f2b(hnew);
    hb[idx] = hq;
    if (hstore) hstore[((long)(b * TSTEP + t) << 10) | j] = hq;
}

// fused attention + gi2 (via precomputed vWih2) + gru2. One block per batch b.
__global__ __launch_bounds__(512) void attn_gru2_kernel(
    const ushort_t* __restrict__ vwb, const float* __restrict__ qgi2,
    const float* __restrict__ qP,
    const ushort_t* __restrict__ vwih2,   // [B*NOBJ*3072] bf16
    const float* __restrict__ gh2, const float* __restrict__ ghP2,
    const int* __restrict__ cap_len, int t,
    float* __restrict__ h2, ushort_t* __restrict__ h2b,
    ushort_t* __restrict__ hstore, float* __restrict__ alpha)
{
    int b = blockIdx.x;
    __shared__ float qs[HID];
    __shared__ float att_s[NOBJ];
    __shared__ float gis[3 * HID];
    int tid = threadIdx.x, lane = tid & 63, w = tid >> 6;   // 8 waves
    const float* qb = qgi2 + (long)b * 4096;

    // q = relu(sum of 4 partials)
    for (int hh = tid; hh < HID; hh += 512) {
        float s = qb[hh];
        for (int sp = 0; sp < 3; sp++) s += qP[(long)sp * 524288 + (long)b * 4096 + hh];
        qs[hh] = fmaxf(s, 0.f);
    }
    __syncthreads();

    for (int o = w; o < NOBJ; o += 8) {
        const ushort_t* vwo = vwb + ((long)b * NOBJ + o) * HID;
        float s = 0.f;
        for (int hh = lane; hh < HID; hh += 64) s += b2f(vwo[hh]) * qs[hh];
        for (int off = 32; off > 0; off >>= 1) s += __shfl_down(s, off);
        if (lane == 0) att_s[o] = s;
    }
    __syncthreads();
    if (tid == 0) {
        float mx = att_s[0];
        for (int o = 1; o < NOBJ; o++) mx = fmaxf(mx, att_s[o]);
        float sum = 0.f;
        for (int o = 0; o < NOBJ; o++) { float e = expf(att_s[o] - mx); att_s[o] = e; sum += e; }
        float inv = 1.f / sum;
        for (int o = 0; o < NOBJ; o++) att_s[o] *= inv;
    }
    __syncthreads();
    bool m = (t < cap_len[b] - 1);
    if (tid < NOBJ) alpha[((long)b * MAXLEN + t) * NOBJ + tid] = m ? att_s[tid] : 0.f;

    // gi2[j] = gi2_h(sum of partials) + sum_o att[o] * vWih2[b,o,j]  (LDS only)
    const ushort_t* vw2 = vwih2 + (long)b * NOBJ * 3072;
    for (int j = tid; j < 3 * HID; j += 512) {
        float s = qb[HID + j];
        for (int sp = 0; sp < 3; sp++) s += qP[(long)sp * 524288 + (long)b * 4096 + HID + j];
        for (int o = 0; o < NOBJ; o++) s += att_s[o] * b2f(vw2[(long)o * 3072 + j]);
        gis[j] = s;
    }
    __syncthreads();

    // gru2
    for (int j = tid; j < HID; j += 512) {
        long o0 = (long)b * 3 * HID + j;
        float hr = gh2[o0], hz = gh2[o0 + HID], hn = gh2[o0 + 2 * HID];
        for (int sp = 0; sp < 3; sp++) {
            const float* hp = ghP2 + (long)sp * 393216;
            hr += hp[o0]; hz += hp[o0 + HID]; hn += hp[o0 + 2 * HID];
        }
        float ir = gis[j], iz = gis[HID + j], in_ = gis[2 * HID + j];
        float r = 1.f / (1.f + expf(-(ir + hr)));
        float z = 1.f / (1.f + expf(-(iz + hz)));
        float n = tanhf(in_ + r * hn);
        int idx = (b << 10) | j;
        float hnew = (1.f - z) * n + z * h2[idx];
        h2[idx] = hnew;
        ushort_t hq = f2b(hnew);
        h2b[idx] = hq;
        hstore[((long)(b * TSTEP + t) << 10) | j] = hq;
    }
}

// row softmax over NTOKEN, single global read via LDS staging
__global__ __launch_bounds__(256) void softmax_kernel(float* __restrict__ predict,
                                                      float* __restrict__ alpha,
                                                      const int* __restrict__ cap_len)
{
    __shared__ float ls[NTOKEN];     // 60000 B
    __shared__ float sred[4];
    int row = blockIdx.x;                 // b*20 + t
    int b = row / MAXLEN, t = row % MAXLEN;
    float* p = predict + (long)row * NTOKEN;
    int tid = threadIdx.x;
    int dec = cap_len[b] - 1;
    if (t >= dec) {
        const float u = 1.0f / (float)NTOKEN;
        for (int i = tid; i < NTOKEN; i += 256) p[i] = u;
        if (t == MAXLEN - 1 && tid < NOBJ) alpha[(long)row * NOBJ + tid] = 0.f;
        return;
    }
    float mx = -3.4e38f;
    for (int i = tid; i < NTOKEN; i += 256) {
        float x = p[i]; ls[i] = x; mx = fmaxf(mx, x);
    }
    for (int off = 32; off > 0; off >>= 1) mx = fmaxf(mx, __shfl_down(mx, off));
    if ((tid & 63) == 0) sred[tid >> 6] = mx;
    __syncthreads();
    mx = fmaxf(fmaxf(sred[0], sred[1]), fmaxf(sred[2], sred[3]));
    __syncthreads();
    float s = 0.f;
    for (int i = tid; i < NTOKEN; i += 256) {
        float e = expf(ls[i] - mx); ls[i] = e; s += e;
    }
    for (int off = 32; off > 0; off >>= 1) s += __shfl_down(s, off);
    if ((tid & 63) == 0) sred[tid >> 6] = s;
    __syncthreads();
    s = sred[0] + sred[1] + sred[2] + sred[3];
    float inv = 1.f / s;
    for (int i = tid; i < NTOKEN; i += 256) p[i] = ls[i] * inv;
}

// ---------------------------------------------------------------------------
extern "C" void kernel_launch(void* const* d_in, const int* in_sizes, int n_in,
                              void* d_out, int out_size, void* d_ws, size_t ws_size,
                              hipStream_t stream)
{
    const float* v       = (const float*)d_in[0];
    const int*   caption = (const int*)  d_in[1];
    const int*   cap_len = (const int*)  d_in[2];
    const float* emb     = (const float*)d_in[3];
    const float* Wih1    = (const float*)d_in[4];
    const float* Whh1    = (const float*)d_in[5];
    const float* bih1    = (const float*)d_in[6];
    const float* bhh1    = (const float*)d_in[7];
    const float* Wih2    = (const float*)d_in[8];
    const float* Whh2    = (const float*)d_in[9];
    const float* bih2    = (const float*)d_in[10];
    const float* bhh2    = (const float*)d_in[11];
    const float* Wfc1    = (const float*)d_in[12];
    const float* bfc1    = (const float*)d_in[13];
    const float* Wfc2    = (const float*)d_in[14];
    const float* bfc2    = (const float*)d_in[15];
    const float* Wv      = (const float*)d_in[16];
    const float* bv      = (const float*)d_in[17];
    const float* Wq      = (const float*)d_in[18];
    const float* bq      = (const float*)d_in[19];
    const float* Wa      = (const float*)d_in[20];
    // ba cancels in softmax

    // ---- workspace layout ----
    float* f32base = (float*)d_ws;
    float* gvm   = f32base;              // 128*3072
    float* gi1s  = gvm   + 393216;       // 2432*3072
    float* h1    = gi1s  + 7471104;      // 128*1024  (h1,h2 contiguous)
    float* h2    = h1    + 131072;
    float* gi    = h2    + 131072;       // 128*3072
    float* gh    = gi    + 393216;
    float* gh2   = gh    + 393216;
    float* qgi2  = gh2   + 393216;       // 128*4096
    float* vmean = qgi2  + 524288;       // 128*2048
    float* bcat2 = vmean + 262144;       // 4096
    ushort_t* ub = (ushort_t*)(bcat2 + 4096);
    ushort_t* Wih1h = ub;                 // 3072*1024
    ushort_t* Wih1c = Wih1h + 3145728;    // 3072*1024
    ushort_t* Whh1b = Wih1c + 3145728;    // 3072*1024
    ushort_t* Whh2b = Whh1b + 3145728;    // 3072*1024
    ushort_t* Wih2v = Whh2b + 3145728;    // 3072*2048
    ushort_t* Wcat2 = Wih2v + 6291456;    // 4096*1024
    ushort_t* Wfc2b = Wcat2 + 4194304;    // 15000*1024 (epilogue) / vwih2 (loop)
    ushort_t* vw_bf = Wfc2b + 15360000;   // 4608*1024
    ushort_t* H2Ab  = vw_bf + 4718592;    // 2432*1024
    ushort_t* h1b   = H2Ab  + 2490368;    // 128*1024 (h1b,h2b contiguous)
    ushort_t* h2b   = h1b   + 131072;
    ushort_t* x2v   = h2b   + 131072;     // 128*2048 (unused, layout kept)
    ushort_t* vmeanb= x2v   + 262144;     // 128*2048
    ushort_t* TEMP  = vmeanb+ 262144;     // 11534336 max
    // vwih2 aliases the Wfc2b region (dead until post-loop): 128*36*3072 = 14155776
    ushort_t* vwih2 = Wfc2b;
    // TEMP sub-uses — prologue scratch (sequential in stream):
    ushort_t* vb     = TEMP;              // 4608*2048
    ushort_t* Wvb    = TEMP + 9437184;    // 1024*2048
    ushort_t* Wqb    = TEMP;              // 1024*1024
    ushort_t* Wih2hb = TEMP + 1048576;    // 3072*1024
    ushort_t* Wfc1T  = TEMP + 4194304;    // 1024*1024
    ushort_t* Wih1m  = TEMP;              // 3072*2048
    ushort_t* Acap   = TEMP;              // 2432*1024
    // TEMP sub-uses — recurrent-loop split-K partials:
    float* TEMPf  = (float*)TEMP;         // 5767168 floats capacity
    float* P_gi   = TEMPf;                // 3 * 393216
    float* P_gh   = P_gi  + 3 * 393216;   // 3 * 393216
    float* P_gh2  = P_gh  + 3 * 393216;   // 3 * 393216
    float* P_q    = P_gh2 + 3 * 393216;   // 3 * 524288  (total 5111808 < 5767168)
    int* tok_idx = (int*)(TEMP + 11534336);
    int* crow20  = tok_idx + BATCH * TSTEP;

    float* out     = (float*)d_out;
    float* predict = out;                                   // 128*20*15000
    float* out1    = out + (long)BATCH * MAXLEN * NTOKEN;   // 128*19
    float* alpha   = out1 + (long)BATCH * TSTEP;            // 128*20*36

    #define CONV(src, ld, rowidx, dst, rows, cols) \
        conv_kernel<<<(int)(((long)(rows)*(cols)/4 + 255)/256), 256, 0, stream>>>( \
            src, ld, rowidx, dst, rows, cols)

    // ---- prologue ----
    init_kernel<<<1024, 256, 0, stream>>>(caption, tok_idx, crow20, h1, h1b);
    sort_caption_kernel<<<1, 128, 0, stream>>>(caption, cap_len, out1);
    vmean_kernel<<<(BATCH * VDIM) / 256, 256, 0, stream>>>(v, vmean, vmeanb);

    CONV(Wih1,        4096, nullptr, Wih1h, 3072, 1024);
    CONV(Wih1 + 3072, 4096, nullptr, Wih1c, 3072, 1024);
    CONV(Whh1,        1024, nullptr, Whh1b, 3072, 1024);
    CONV(Whh2,        1024, nullptr, Whh2b, 3072, 1024);
    CONV(Wih2,        3072, nullptr, Wih2v, 3072, 2048);

    // vw = relu(v @ Wv^T + bv) * Wa  -> bf16 [4608 x 1024]
    CONV(v,  2048, nullptr, vb,  4608, 2048);
    CONV(Wv, 2048, nullptr, Wvb, 1024, 2048);
    mfma_gemm<8, true><<<dim3(8, 36), 256, 0, stream>>>(
        vb, 2048, nullptr, Wvb, 2048, vw_bf, 1024, nullptr,
        bv, Wa, nullptr, 0, 1, 1024, 1024, 2048, 1);

    // vWih2[b,o,:] = v[b,o,:] @ Wih2[:, :2048]^T  -> bf16 [4608 x 3072]
    mfma_gemm<8, true><<<dim3(24, 36), 256, 0, stream>>>(
        vb, 2048, nullptr, Wih2v, 2048, vwih2, 3072, nullptr,
        nullptr, nullptr, nullptr, 0, 1, 0, 3072, 2048, 1);

    // folded weights: Wcat2 = [Wq@Wfc1 ; Wih2[:,2048:]@Wfc1]
    CONV(Wq,          1024, nullptr, Wqb,    1024, 1024);
    CONV(Wih2 + 2048, 3072, nullptr, Wih2hb, 3072, 1024);
    transpose_conv_kernel<<<dim3(32, 32), 256, 0, stream>>>(Wfc1, Wfc1T);
    mfma_gemm<8, true><<<dim3(8, 8), 256, 0, stream>>>(
        Wqb, 1024, nullptr, Wfc1T, 1024, Wcat2, 1024, nullptr,
        nullptr, nullptr, nullptr, 0, 1, 0, 1024, 1024, 1);
    mfma_gemm<8, true><<<dim3(8, 24), 256, 0, stream>>>(
        Wih2hb, 1024, nullptr, Wfc1T, 1024, Wcat2 + 1048576, 1024, nullptr,
        nullptr, nullptr, nullptr, 0, 1, 0, 1024, 1024, 1);
    bias_fold_kernel<<<64, 256, 0, stream>>>(Wq, Wih2, bfc1, bq, bih2, bcat2);

    // gvm = vmean @ Wih1[:,1024:3072]^T + bih1  (f32 [128 x 3072])
    CONV(Wih1 + 1024, 4096, nullptr, Wih1m, 3072, 2048);
    mfma_gemm<8, false><<<dim3(24, 1), 256, 0, stream>>>(
        vmeanb, 2048, nullptr, Wih1m, 2048, gvm, 3072, nullptr,
        bih1, nullptr, nullptr, 0, 1, 0, 3072, 2048, 0);

    // gi1s[b*19+t] = emb[cap[b,t]] @ Wih1[:,3072:]^T + gvm[b]
    CONV(emb, 1024, tok_idx, Acap, 2432, 1024);
    mfma_gemm<8, false><<<dim3(24, 19), 256, 0, stream>>>(
        Acap, 1024, nullptr, Wih1c, 1024, gi1s, 3072, nullptr,
        nullptr, nullptr, gvm, 3072, TSTEP, 0, 3072, 1024, 1);

    // ---- recurrent loop: 4 launches/step ----
    for (int t = 0; t < TSTEP; t++) {
        step3_kernel<2, 4><<<dim3(96, 4, 3), 256, 0, stream>>>(
            h1b, h2b, Wih1h, Whh1b, Whh2b, gi, gh, gh2,
            P_gi, P_gh, P_gh2, gi1s + (long)t * 3072, bhh1, bhh2);
        gru_kernel<<<512, 256, 0, stream>>>(gi, P_gi, gh, P_gh, 3, h1, h1b, nullptr, t);
        // [q | gi2_h] = h1' @ Wcat2^T + bcat2 (relu deferred)
        splitk_gemm<2, 4><<<dim3(128, 4), 256, 0, stream>>>(
            h1b, 1024, Wcat2, 1024, qgi2, P_q, 524288, 4096,
            bcat2, nullptr, 0, 4096, 1024);
        attn_gru2_kernel<<<BATCH, 512, 0, stream>>>(
            vw_bf, qgi2, P_q, vwih2, gh2, P_gh2, cap_len, t,
            h2, h2b, H2Ab, alpha);
    }

    // ---- epilogue (Wfc2b conversion deferred: region held vWih2 in loop) ----
    CONV(Wfc2, 1024, nullptr, Wfc2b, NTOKEN, 1024);
    mfma_gemm<8, false><<<dim3(118, 19), 256, 0, stream>>>(
        H2Ab, 1024, nullptr, Wfc2b, 1024, predict, NTOKEN, crow20,
        bfc2, nullptr, nullptr, 0, 1, 0, NTOKEN, 1024, 1);
    softmax_kernel<<<BATCH * MAXLEN, 256, 0, stream>>>(predict, alpha, cap_len);
    #undef CONV
}

// Round 6
// 1933.677 us; speedup vs baseline: 1.4898x; 1.2188x over previous
//
#include <hip/hip_runtime.h>
#include <math.h>

#define NTOKEN 15000
#define EMBED  1024
#define HID    1024
#define VDIM   2048
#define MAXLEN 20
#define BATCH  128
#define NOBJ   36
#define TSTEP  19

typedef unsigned short ushort_t;
typedef __attribute__((ext_vector_type(8))) short short8;
typedef __attribute__((ext_vector_type(4))) float floatx4;

__device__ __forceinline__ float b2f(ushort_t u) {
    return __uint_as_float(((unsigned)u) << 16);
}
__device__ __forceinline__ ushort_t f2b(float f) {
    unsigned x = __float_as_uint(f);
    unsigned r = (x + 0x7fffu + ((x >> 16) & 1u)) >> 16;
    return (ushort_t)r;
}

// async global->LDS, 16B per lane; LDS dest = wave-uniform base + lane*16
__device__ __forceinline__ void gload16(const ushort_t* g, ushort_t* l) {
    __builtin_amdgcn_global_load_lds(
        (const __attribute__((address_space(1))) unsigned int*)g,
        (__attribute__((address_space(3))) unsigned int*)l, 16, 0, 0);
}

// ---------------------------------------------------------------------------
// MFMA bf16 GEMM core, v3: global_load_lds staging (no VGPR staging, no
// ds_write), LDS double-buffer, 1 barrier/k-iter.
// LDS layout: linear [rows][32] ushorts (64 B/row), 16B chunks XOR-swizzled:
// physical chunk c holds global chunk c^(row&3); reads apply the same XOR.
// => conflict-free b128 reads AND linear gload_lds writes (rule 21).
// C[crow?[m]][n] = post( A[arow?[m]][k0:k0+K] @ B^T ), BM=128, BN=NF*16,
// K % 32 == 0. N guarded.
// ---------------------------------------------------------------------------
template<int NF, bool OUT_BF16>
__device__ __forceinline__ void mfma_core(
    ushort_t* As, ushort_t* Bs,     // As[2][128*32], Bs[2][NF*16*32]
    const ushort_t* __restrict__ A, int lda, const int* __restrict__ arow,
    const ushort_t* __restrict__ B, int ldb,
    void* __restrict__ Cv, int ldc, const int* __restrict__ crow,
    const float* __restrict__ bias, const float* __restrict__ mulvec,
    const float* __restrict__ cadd, long ldadd, int cadd_div,
    int relu_n, int N, int K, int m0, int n0, int k0)
{
    constexpr int ABUF = 128 * 32;
    constexpr int BBUF = NF * 16 * 32;
    const int tid  = threadIdx.x;
    const int lane = tid & 63;
    const int w    = tid >> 6;

    floatx4 acc[2][NF];
#pragma unroll
    for (int mf = 0; mf < 2; mf++)
#pragma unroll
        for (int nf = 0; nf < NF; nf++) acc[mf][nf] = (floatx4){0.f, 0.f, 0.f, 0.f};

    // staging source coords: wave w, instr j covers rows w*R + j*16 + (lane>>2),
    // chunk (lane&3); source chunk swizzled by ^(row&3).
    const int sr = lane >> 2;
    const int sc = lane & 3;

    int ra0 = w * 32 + sr;
    int ra1 = ra0 + 16;
    int ga0 = m0 + ra0; if (arow) ga0 = arow[ga0];
    int ga1 = m0 + ra1; if (arow) ga1 = arow[ga1];
    const ushort_t* srcA0 = A + (long)ga0 * lda + k0 + ((sc ^ (ra0 & 3)) * 8);
    const ushort_t* srcA1 = A + (long)ga1 * lda + k0 + ((sc ^ (ra1 & 3)) * 8);

    const ushort_t* srcB0;
    const ushort_t* srcB1 = nullptr;
    if constexpr (NF == 8) {
        int rb0 = w * 32 + sr, rb1 = rb0 + 16;
        int gb0 = n0 + rb0; if (gb0 >= N) gb0 = N - 1;
        int gb1 = n0 + rb1; if (gb1 >= N) gb1 = N - 1;
        srcB0 = B + (long)gb0 * ldb + k0 + ((sc ^ (rb0 & 3)) * 8);
        srcB1 = B + (long)gb1 * ldb + k0 + ((sc ^ (rb1 & 3)) * 8);
    } else {
        int rb0 = w * 16 + sr;          // NF=4: waves 0..3; NF=2: waves 0..1
        int gb0 = n0 + rb0; if (gb0 >= N) gb0 = N - 1;
        srcB0 = B + (long)gb0 * ldb + k0 + ((sc ^ (rb0 & 3)) * 8);
    }

    ushort_t* Abase = As + w * 1024;                    // + p*ABUF (+512 for j=1)
    ushort_t* Bbase = (NF == 8) ? (Bs + w * 1024) : (Bs + w * 512);

    auto STAGE = [&](int p, int kk) {
        gload16(srcA0 + kk, Abase + p * ABUF);
        gload16(srcA1 + kk, Abase + p * ABUF + 512);
        if constexpr (NF == 8) {
            gload16(srcB0 + kk, Bbase + p * BBUF);
            gload16(srcB1 + kk, Bbase + p * BBUF + 512);
        } else if constexpr (NF == 4) {
            gload16(srcB0 + kk, Bbase + p * BBUF);
        } else {
            if (w < 2) gload16(srcB0 + kk, Bbase + p * BBUF);
        }
    };

    const int fr   = lane & 15;
    const int aoff = (((lane >> 4) ^ (fr & 3)) * 8);    // swizzled 16B chunk

    auto CMP = [&](const ushort_t* Ap, const ushort_t* Bp) {
        short8 bfr[NF];
#pragma unroll
        for (int nf = 0; nf < NF; nf++)
            bfr[nf] = *(const short8*)(Bp + (nf * 16 + fr) * 32 + aoff);
#pragma unroll
        for (int mf = 0; mf < 2; mf++) {
            short8 af = *(const short8*)(Ap + (w * 32 + mf * 16 + fr) * 32 + aoff);
#pragma unroll
            for (int nf = 0; nf < NF; nf++)
                acc[mf][nf] = __builtin_amdgcn_mfma_f32_16x16x32_bf16(
                    af, bfr[nf], acc[mf][nf], 0, 0, 0);
        }
    };

    const int T = K >> 5;
    STAGE(0, 0);
    __syncthreads();                    // drains vmcnt(0): buf0 ready
    int p = 0;
    for (int i = 0; i < T; i++) {
        if (i + 1 < T) STAGE(p ^ 1, (i + 1) * 32);
        CMP(As + p * ABUF, Bs + p * BBUF);
        __syncthreads();                // all reads of p done; loads into p^1 done
        p ^= 1;
    }

    const int rq = lane >> 4;
#pragma unroll
    for (int mf = 0; mf < 2; mf++) {
#pragma unroll
        for (int r = 0; r < 4; r++) {
            int m = m0 + w * 32 + mf * 16 + rq * 4 + r;
            int cm = crow ? crow[m] : m;
            const float* caddrow = cadd ? (cadd + (long)(m / cadd_div) * ldadd) : nullptr;
#pragma unroll
            for (int nf = 0; nf < NF; nf++) {
                int n = n0 + nf * 16 + fr;
                if (n < N) {
                    float val = acc[mf][nf][r];
                    if (bias)    val += bias[n];
                    if (caddrow) val += caddrow[n];
                    if (n < relu_n) val = fmaxf(val, 0.f);
                    if (mulvec)  val *= mulvec[n];
                    if (OUT_BF16) ((ushort_t*)Cv)[(long)cm * ldc + n] = f2b(val);
                    else          ((float*)Cv)[(long)cm * ldc + n]   = val;
                }
            }
        }
    }
}

// standalone GEMM; swz!=0 -> XCD-bijective n-slab swizzle (L2 locality)
template<int NF, bool OUT_BF16>
__global__ __launch_bounds__(256) void mfma_gemm(
    const ushort_t* __restrict__ A, int lda, const int* __restrict__ arow,
    const ushort_t* __restrict__ B, int ldb,
    void* __restrict__ C, int ldc, const int* __restrict__ crow,
    const float* __restrict__ bias, const float* __restrict__ mulvec,
    const float* __restrict__ cadd, long ldadd, int cadd_div,
    int relu_n, int N, int K, int swz)
{
    __shared__ ushort_t As[2 * 128 * 32];
    __shared__ ushort_t Bs[2 * NF * 16 * 32];
    int mt = blockIdx.y, nt = blockIdx.x;
    if (swz) {
        int D = gridDim.x * gridDim.y;
        int d = blockIdx.y * gridDim.x + blockIdx.x;   // dispatch-linear id
        int x = d & 7, j = d >> 3, q = D >> 3, r = D & 7;
        int g = x * q + (x < r ? x : r) + j;
        mt = g % gridDim.y; nt = g / gridDim.y;
    }
    mfma_core<NF, OUT_BF16>(As, Bs, A, lda, arow, B, ldb, C, ldc, crow,
                            bias, mulvec, cadd, ldadd, cadd_div, relu_n,
                            N, K, mt * 128, nt * (NF * 16), 0);
}

// split-K GEMM: blockIdx.y = split s; split 0 -> C0 (+bias/cadd), s>0 -> CP[s-1]
template<int NF, int KS>
__global__ __launch_bounds__(256) void splitk_gemm(
    const ushort_t* __restrict__ A, int lda,
    const ushort_t* __restrict__ B, int ldb,
    float* __restrict__ C0, float* __restrict__ CP, long pstride, int ldc,
    const float* __restrict__ bias,
    const float* __restrict__ cadd, long ldadd,
    int N, int K)
{
    __shared__ ushort_t As[2 * 128 * 32];
    __shared__ ushort_t Bs[2 * NF * 16 * 32];
    const int s = blockIdx.y;
    const int Kc = K / KS;
    float* C = (s == 0) ? C0 : (CP + (long)(s - 1) * pstride);
    mfma_core<NF, false>(As, Bs, A, lda, nullptr, B, ldb, C, ldc, nullptr,
                         s == 0 ? bias : nullptr, nullptr,
                         s == 0 ? cadd : nullptr, ldadd, 1,
                         0, N, Kc, 0, blockIdx.x * (NF * 16), s * Kc);
}

// fused per-step GEMM trio with split-K: z=0 gi1, z=1 gh1, z=2 gh2
template<int NF, int KS>
__global__ __launch_bounds__(256) void step3_kernel(
    const ushort_t* __restrict__ h1b, const ushort_t* __restrict__ h2b,
    const ushort_t* __restrict__ Wih1h, const ushort_t* __restrict__ Whh1b,
    const ushort_t* __restrict__ Whh2b,
    float* __restrict__ gi, float* __restrict__ gh, float* __restrict__ gh2,
    float* __restrict__ P_gi, float* __restrict__ P_gh, float* __restrict__ P_gh2,
    const float* __restrict__ gi1s_t,
    const float* __restrict__ bhh1, const float* __restrict__ bhh2)
{
    __shared__ ushort_t As[2 * 128 * 32];
    __shared__ ushort_t Bs[2 * NF * 16 * 32];
    const int s = blockIdx.y;
    const int Kc = 1024 / KS;
    const ushort_t* A; const ushort_t* B; float* C0; float* CP;
    const float* bias = nullptr; const float* cadd = nullptr;
    if (blockIdx.z == 0)      { A = h2b; B = Wih1h; C0 = gi;  CP = P_gi;  cadd = gi1s_t; }
    else if (blockIdx.z == 1) { A = h1b; B = Whh1b; C0 = gh;  CP = P_gh;  bias = bhh1; }
    else                      { A = h2b; B = Whh2b; C0 = gh2; CP = P_gh2; bias = bhh2; }
    float* C = (s == 0) ? C0 : (CP + (long)(s - 1) * 393216);
    mfma_core<NF, false>(As, Bs, A, 1024, nullptr, B, 1024, C, 3072, nullptr,
                         s == 0 ? bias : nullptr, nullptr,
                         s == 0 ? cadd : nullptr, (long)TSTEP * 3072, 1, 0,
                         3072, Kc, 0, blockIdx.x * (NF * 16), s * Kc);
}

// ---------------------------------------------------------------------------
// small helper kernels
// ---------------------------------------------------------------------------
__global__ void init_kernel(const int* __restrict__ caption,
                            int* __restrict__ tok_idx, int* __restrict__ crow20,
                            float* __restrict__ h12f, ushort_t* __restrict__ h12b)
{
    int idx = blockIdx.x * 256 + threadIdx.x;   // 262144 threads
    if (idx < BATCH * TSTEP) {
        int b = idx / TSTEP, t = idx % TSTEP;
        tok_idx[idx] = caption[b * MAXLEN + t];
        crow20[idx]  = b * MAXLEN + t;
    }
    h12f[idx] = 0.f;
    h12b[idx] = 0;
}

__global__ void sort_caption_kernel(const int* __restrict__ caption,
                                    const int* __restrict__ cap_len,
                                    float* __restrict__ out1)
{
    int i = threadIdx.x;
    if (i < BATCH) {
        int li = cap_len[i];
        int rank = 0;
        for (int j = 0; j < BATCH; j++) {
            int lj = cap_len[j];
            if (lj > li || (lj == li && j < i)) rank++;
        }
        for (int k = 0; k < TSTEP; k++)
            out1[rank * TSTEP + k] = (float)caption[i * MAXLEN + 1 + k];
    }
}

__global__ void vmean_kernel(const float* __restrict__ v,
                             float* __restrict__ vmean, ushort_t* __restrict__ vmeanb)
{
    int idx = blockIdx.x * 256 + threadIdx.x;   // BATCH*VDIM
    int b = idx >> 11, d = idx & (VDIM - 1);
    float s = 0.f;
    for (int o = 0; o < NOBJ; o++) s += v[((long)b * NOBJ + o) * VDIM + d];
    float m = s * (1.0f / 36.0f);
    vmean[idx] = m;
    vmeanb[idx] = f2b(m);
}

// strided (optionally row-gathered) f32 -> bf16 convert, 4 elems/thread
__global__ void conv_kernel(const float* __restrict__ src, long ld,
                            const int* __restrict__ rowidx,
                            ushort_t* __restrict__ dst, int rows, int cols)
{
    long idx4 = ((long)blockIdx.x * 256 + threadIdx.x) * 4;
    if (idx4 >= (long)rows * cols) return;
    int r = (int)(idx4 / cols);
    int c = (int)(idx4 % cols);
    long sr = rowidx ? rowidx[r] : r;
    float4 f = *(const float4*)(src + sr * ld + c);
    dst[idx4 + 0] = f2b(f.x);
    dst[idx4 + 1] = f2b(f.y);
    dst[idx4 + 2] = f2b(f.z);
    dst[idx4 + 3] = f2b(f.w);
}

// Wfc1 [1024x1024] -> Wfc1T bf16 (dst[n*1024+k] = src[k*1024+n])
__global__ void transpose_conv_kernel(const float* __restrict__ src,
                                      ushort_t* __restrict__ dst)
{
    __shared__ float tile[32][33];
    int bx = blockIdx.x, by = blockIdx.y;
    int lx = threadIdx.x & 31, ly = threadIdx.x >> 5;   // ly 0..7
    for (int i = 0; i < 32; i += 8)
        tile[ly + i][lx] = src[(long)(by * 32 + ly + i) * 1024 + bx * 32 + lx];
    __syncthreads();
    for (int i = 0; i < 32; i += 8)
        dst[(long)(bx * 32 + ly + i) * 1024 + by * 32 + lx] = f2b(tile[lx][ly + i]);
}

// bcat2[0:1024] = bq + Wq @ bfc1 ; bcat2[1024:4096] = bih2 + Wih2[:,2048:] @ bfc1
__global__ void bias_fold_kernel(const float* __restrict__ Wq,
                                 const float* __restrict__ Wih2,
                                 const float* __restrict__ bfc1,
                                 const float* __restrict__ bq,
                                 const float* __restrict__ bih2,
                                 float* __restrict__ bcat2)
{
    int wave = blockIdx.x * 4 + (threadIdx.x >> 6);
    int lane = threadIdx.x & 63;
    for (int n = wave; n < 4096; n += 256) {
        const float* wrow = (n < 1024) ? (Wq + (long)n * 1024)
                                       : (Wih2 + (long)(n - 1024) * 3072 + 2048);
        float s = 0.f;
        for (int j = lane; j < 1024; j += 64) s += wrow[j] * bfc1[j];
        for (int off = 32; off > 0; off >>= 1) s += __shfl_down(s, off);
        if (lane == 0) bcat2[n] = s + ((n < 1024) ? bq[n] : bih2[n - 1024]);
    }
}

// GRU combine (gru1): gate = gi + sum_s giP[s] ; same for gh
__global__ void gru_kernel(const float* __restrict__ gi, const float* __restrict__ giP,
                           const float* __restrict__ gh, const float* __restrict__ ghP,
                           int nsp,
                           float* __restrict__ h, ushort_t* __restrict__ hb,
                           ushort_t* __restrict__ hstore, int t)
{
    int idx = blockIdx.x * 256 + threadIdx.x;   // BATCH*HID
    int b = idx >> 10, j = idx & (HID - 1);
    long o0 = (long)b * 3 * HID + j;
    float ir = gi[o0], iz = gi[o0 + HID], in_ = gi[o0 + 2 * HID];
    float hr = gh[o0], hz = gh[o0 + HID], hn  = gh[o0 + 2 * HID];
    for (int s = 0; s < nsp; s++) {
        const float* gp = giP + (long)s * 393216;
        const float* hp = ghP + (long)s * 393216;
        ir  += gp[o0]; iz += gp[o0 + HID]; in_ += gp[o0 + 2 * HID];
        hr  += hp[o0]; hz += hp[o0 + HID]; hn  += hp[o0 + 2 * HID];
    }
    float r = 1.f / (1.f + expf(-(ir + hr)));
    float z = 1.f / (1.f + expf(-(iz + hz)));
    float n = tanhf(in_ + r * hn);
    float hnew = (1.f - z) * n + z * h[idx];
    h[idx] = hnew;
    ushort_t hq = f2b(hnew);
    hb[idx] = hq;
    if (hstore) hstore[((long)(b * TSTEP + t) << 10) | j] = hq;
}

// fused attention + gi2 (via precomputed vWih2) + gru2. One block per batch b.
__global__ __launch_bounds__(512) void attn_gru2_kernel(
    const ushort_t* __restrict__ vwb, const float* __restrict__ qgi2,
    const float* __restrict__ qP,
    const ushort_t* __restrict__ vwih2,   // [B*NOBJ*3072] bf16
    const float* __restrict__ gh2, const float* __restrict__ ghP2,
    const int* __restrict__ cap_len, int t,
    float* __restrict__ h2, ushort_t* __restrict__ h2b,
    ushort_t* __restrict__ hstore, float* __restrict__ alpha)
{
    int b = blockIdx.x;
    __shared__ float qs[HID];
    __shared__ float att_s[NOBJ];
    __shared__ float gis[3 * HID];
    int tid = threadIdx.x, lane = tid & 63, w = tid >> 6;   // 8 waves
    const float* qb = qgi2 + (long)b * 4096;

    // q = relu(sum of 4 partials)
    for (int hh = tid; hh < HID; hh += 512) {
        float s = qb[hh];
        for (int sp = 0; sp < 3; sp++) s += qP[(long)sp * 524288 + (long)b * 4096 + hh];
        qs[hh] = fmaxf(s, 0.f);
    }
    __syncthreads();

    for (int o = w; o < NOBJ; o += 8) {
        const ushort_t* vwo = vwb + ((long)b * NOBJ + o) * HID;
        float s = 0.f;
        for (int hh = lane * 8; hh < HID; hh += 512) {   // 2 iters, short8 loads
            short8 v8 = *(const short8*)(vwo + hh);
#pragma unroll
            for (int k = 0; k < 8; k++) s += b2f((ushort_t)v8[k]) * qs[hh + k];
        }
        for (int off = 32; off > 0; off >>= 1) s += __shfl_down(s, off);
        if (lane == 0) att_s[o] = s;
    }
    __syncthreads();
    if (tid == 0) {
        float mx = att_s[0];
        for (int o = 1; o < NOBJ; o++) mx = fmaxf(mx, att_s[o]);
        float sum = 0.f;
        for (int o = 0; o < NOBJ; o++) { float e = expf(att_s[o] - mx); att_s[o] = e; sum += e; }
        float inv = 1.f / sum;
        for (int o = 0; o < NOBJ; o++) att_s[o] *= inv;
    }
    __syncthreads();
    bool m = (t < cap_len[b] - 1);
    if (tid < NOBJ) alpha[((long)b * MAXLEN + t) * NOBJ + tid] = m ? att_s[tid] : 0.f;

    // gi2[j] = gi2_h(sum of partials) + sum_o att[o] * vWih2[b,o,j]  (LDS only)
    const ushort_t* vw2 = vwih2 + (long)b * NOBJ * 3072;
    for (int j0 = tid * 8; j0 < 3 * HID; j0 += 512 * 8) {
        float sv[8];
        float4 qa = *(const float4*)(qb + HID + j0);
        float4 qc = *(const float4*)(qb + HID + j0 + 4);
        sv[0] = qa.x; sv[1] = qa.y; sv[2] = qa.z; sv[3] = qa.w;
        sv[4] = qc.x; sv[5] = qc.y; sv[6] = qc.z; sv[7] = qc.w;
        for (int sp = 0; sp < 3; sp++) {
            const float* qpp = qP + (long)sp * 524288 + (long)b * 4096 + HID + j0;
            float4 pa = *(const float4*)(qpp);
            float4 pc = *(const float4*)(qpp + 4);
            sv[0] += pa.x; sv[1] += pa.y; sv[2] += pa.z; sv[3] += pa.w;
            sv[4] += pc.x; sv[5] += pc.y; sv[6] += pc.z; sv[7] += pc.w;
        }
        for (int o = 0; o < NOBJ; o++) {
            float a = att_s[o];
            short8 v8 = *(const short8*)(vw2 + (long)o * 3072 + j0);
#pragma unroll
            for (int k = 0; k < 8; k++) sv[k] += a * b2f((ushort_t)v8[k]);
        }
#pragma unroll
        for (int k = 0; k < 8; k++) gis[j0 + k] = sv[k];
    }
    __syncthreads();

    // gru2
    for (int j = tid; j < HID; j += 512) {
        long o0 = (long)b * 3 * HID + j;
        float hr = gh2[o0], hz = gh2[o0 + HID], hn = gh2[o0 + 2 * HID];
        for (int sp = 0; sp < 3; sp++) {
            const float* hp = ghP2 + (long)sp * 393216;
            hr += hp[o0]; hz += hp[o0 + HID]; hn += hp[o0 + 2 * HID];
        }
        float ir = gis[j], iz = gis[HID + j], in_ = gis[2 * HID + j];
        float r = 1.f / (1.f + expf(-(ir + hr)));
        float z = 1.f / (1.f + expf(-(iz + hz)));
        float n = tanhf(in_ + r * hn);
        int idx = (b << 10) | j;
        float hnew = (1.f - z) * n + z * h2[idx];
        h2[idx] = hnew;
        ushort_t hq = f2b(hnew);
        h2b[idx] = hq;
        hstore[((long)(b * TSTEP + t) << 10) | j] = hq;
    }
}

// row softmax over NTOKEN, single global read via LDS staging
__global__ __launch_bounds__(256) void softmax_kernel(float* __restrict__ predict,
                                                      float* __restrict__ alpha,
                                                      const int* __restrict__ cap_len)
{
    __shared__ float ls[NTOKEN];     // 60000 B
    __shared__ float sred[4];
    int row = blockIdx.x;                 // b*20 + t
    int b = row / MAXLEN, t = row % MAXLEN;
    float* p = predict + (long)row * NTOKEN;
    int tid = threadIdx.x;
    int dec = cap_len[b] - 1;
    if (t >= dec) {
        const float u = 1.0f / (float)NTOKEN;
        for (int i = tid; i < NTOKEN; i += 256) p[i] = u;
        if (t == MAXLEN - 1 && tid < NOBJ) alpha[(long)row * NOBJ + tid] = 0.f;
        return;
    }
    float mx = -3.4e38f;
    for (int i = tid; i < NTOKEN; i += 256) {
        float x = p[i]; ls[i] = x; mx = fmaxf(mx, x);
    }
    for (int off = 32; off > 0; off >>= 1) mx = fmaxf(mx, __shfl_down(mx, off));
    if ((tid & 63) == 0) sred[tid >> 6] = mx;
    __syncthreads();
    mx = fmaxf(fmaxf(sred[0], sred[1]), fmaxf(sred[2], sred[3]));
    __syncthreads();
    float s = 0.f;
    for (int i = tid; i < NTOKEN; i += 256) {
        float e = expf(ls[i] - mx); ls[i] = e; s += e;
    }
    for (int off = 32; off > 0; off >>= 1) s += __shfl_down(s, off);
    if ((tid & 63) == 0) sred[tid >> 6] = s;
    __syncthreads();
    s = sred[0] + sred[1] + sred[2] + sred[3];
    float inv = 1.f / s;
    for (int i = tid; i < NTOKEN; i += 256) p[i] = ls[i] * inv;
}

// ---------------------------------------------------------------------------
extern "C" void kernel_launch(void* const* d_in, const int* in_sizes, int n_in,
                              void* d_out, int out_size, void* d_ws, size_t ws_size,
                              hipStream_t stream)
{
    const float* v       = (const float*)d_in[0];
    const int*   caption = (const int*)  d_in[1];
    const int*   cap_len = (const int*)  d_in[2];
    const float* emb     = (const float*)d_in[3];
    const float* Wih1    = (const float*)d_in[4];
    const float* Whh1    = (const float*)d_in[5];
    const float* bih1    = (const float*)d_in[6];
    const float* bhh1    = (const float*)d_in[7];
    const float* Wih2    = (const float*)d_in[8];
    const float* Whh2    = (const float*)d_in[9];
    const float* bih2    = (const float*)d_in[10];
    const float* bhh2    = (const float*)d_in[11];
    const float* Wfc1    = (const float*)d_in[12];
    const float* bfc1    = (const float*)d_in[13];
    const float* Wfc2    = (const float*)d_in[14];
    const float* bfc2    = (const float*)d_in[15];
    const float* Wv      = (const float*)d_in[16];
    const float* bv      = (const float*)d_in[17];
    const float* Wq      = (const float*)d_in[18];
    const float* bq      = (const float*)d_in[19];
    const float* Wa      = (const float*)d_in[20];
    // ba cancels in softmax

    // ---- workspace layout ----
    float* f32base = (float*)d_ws;
    float* gvm   = f32base;              // 128*3072
    float* gi1s  = gvm   + 393216;       // 2432*3072
    float* h1    = gi1s  + 7471104;      // 128*1024  (h1,h2 contiguous)
    float* h2    = h1    + 131072;
    float* gi    = h2    + 131072;       // 128*3072
    float* gh    = gi    + 393216;
    float* gh2   = gh    + 393216;
    float* qgi2  = gh2   + 393216;       // 128*4096
    float* vmean = qgi2  + 524288;       // 128*2048
    float* bcat2 = vmean + 262144;       // 4096
    ushort_t* ub = (ushort_t*)(bcat2 + 4096);
    ushort_t* Wih1h = ub;                 // 3072*1024
    ushort_t* Wih1c = Wih1h + 3145728;    // 3072*1024
    ushort_t* Whh1b = Wih1c + 3145728;    // 3072*1024
    ushort_t* Whh2b = Whh1b + 3145728;    // 3072*1024
    ushort_t* Wih2v = Whh2b + 3145728;    // 3072*2048
    ushort_t* Wcat2 = Wih2v + 6291456;    // 4096*1024
    ushort_t* Wfc2b = Wcat2 + 4194304;    // 15000*1024 (epilogue) / vwih2 (loop)
    ushort_t* vw_bf = Wfc2b + 15360000;   // 4608*1024
    ushort_t* H2Ab  = vw_bf + 4718592;    // 2432*1024
    ushort_t* h1b   = H2Ab  + 2490368;    // 128*1024 (h1b,h2b contiguous)
    ushort_t* h2b   = h1b   + 131072;
    ushort_t* x2v   = h2b   + 131072;     // 128*2048 (unused, layout kept)
    ushort_t* vmeanb= x2v   + 262144;     // 128*2048
    ushort_t* TEMP  = vmeanb+ 262144;     // 11534336 max
    // vwih2 aliases the Wfc2b region (dead until post-loop): 128*36*3072 = 14155776
    ushort_t* vwih2 = Wfc2b;
    // TEMP sub-uses — prologue scratch (sequential in stream):
    ushort_t* vb     = TEMP;              // 4608*2048
    ushort_t* Wvb    = TEMP + 9437184;    // 1024*2048
    ushort_t* Wqb    = TEMP;              // 1024*1024
    ushort_t* Wih2hb = TEMP + 1048576;    // 3072*1024
    ushort_t* Wfc1T  = TEMP + 4194304;    // 1024*1024
    ushort_t* Wih1m  = TEMP;              // 3072*2048
    ushort_t* Acap   = TEMP;              // 2432*1024
    // TEMP sub-uses — recurrent-loop split-K partials:
    float* TEMPf  = (float*)TEMP;         // 5767168 floats capacity
    float* P_gi   = TEMPf;                // 3 * 393216
    float* P_gh   = P_gi  + 3 * 393216;   // 3 * 393216
    float* P_gh2  = P_gh  + 3 * 393216;   // 3 * 393216
    float* P_q    = P_gh2 + 3 * 393216;   // 3 * 524288  (total 5111808 < 5767168)
    int* tok_idx = (int*)(TEMP + 11534336);
    int* crow20  = tok_idx + BATCH * TSTEP;

    float* out     = (float*)d_out;
    float* predict = out;                                   // 128*20*15000
    float* out1    = out + (long)BATCH * MAXLEN * NTOKEN;   // 128*19
    float* alpha   = out1 + (long)BATCH * TSTEP;            // 128*20*36

    #define CONV(src, ld, rowidx, dst, rows, cols) \
        conv_kernel<<<(int)(((long)(rows)*(cols)/4 + 255)/256), 256, 0, stream>>>( \
            src, ld, rowidx, dst, rows, cols)

    // ---- prologue ----
    init_kernel<<<1024, 256, 0, stream>>>(caption, tok_idx, crow20, h1, h1b);
    sort_caption_kernel<<<1, 128, 0, stream>>>(caption, cap_len, out1);
    vmean_kernel<<<(BATCH * VDIM) / 256, 256, 0, stream>>>(v, vmean, vmeanb);

    CONV(Wih1,        4096, nullptr, Wih1h, 3072, 1024);
    CONV(Wih1 + 3072, 4096, nullptr, Wih1c, 3072, 1024);
    CONV(Whh1,        1024, nullptr, Whh1b, 3072, 1024);
    CONV(Whh2,        1024, nullptr, Whh2b, 3072, 1024);
    CONV(Wih2,        3072, nullptr, Wih2v, 3072, 2048);

    // vw = relu(v @ Wv^T + bv) * Wa  -> bf16 [4608 x 1024]
    CONV(v,  2048, nullptr, vb,  4608, 2048);
    CONV(Wv, 2048, nullptr, Wvb, 1024, 2048);
    mfma_gemm<8, true><<<dim3(8, 36), 256, 0, stream>>>(
        vb, 2048, nullptr, Wvb, 2048, vw_bf, 1024, nullptr,
        bv, Wa, nullptr, 0, 1, 1024, 1024, 2048, 1);

    // vWih2[b,o,:] = v[b,o,:] @ Wih2[:, :2048]^T  -> bf16 [4608 x 3072]
    mfma_gemm<8, true><<<dim3(24, 36), 256, 0, stream>>>(
        vb, 2048, nullptr, Wih2v, 2048, vwih2, 3072, nullptr,
        nullptr, nullptr, nullptr, 0, 1, 0, 3072, 2048, 1);

    // folded weights: Wcat2 = [Wq@Wfc1 ; Wih2[:,2048:]@Wfc1]
    CONV(Wq,          1024, nullptr, Wqb,    1024, 1024);
    CONV(Wih2 + 2048, 3072, nullptr, Wih2hb, 3072, 1024);
    transpose_conv_kernel<<<dim3(32, 32), 256, 0, stream>>>(Wfc1, Wfc1T);
    mfma_gemm<8, true><<<dim3(8, 8), 256, 0, stream>>>(
        Wqb, 1024, nullptr, Wfc1T, 1024, Wcat2, 1024, nullptr,
        nullptr, nullptr, nullptr, 0, 1, 0, 1024, 1024, 1);
    mfma_gemm<8, true><<<dim3(8, 24), 256, 0, stream>>>(
        Wih2hb, 1024, nullptr, Wfc1T, 1024, Wcat2 + 1048576, 1024, nullptr,
        nullptr, nullptr, nullptr, 0, 1, 0, 1024, 1024, 1);
    bias_fold_kernel<<<64, 256, 0, stream>>>(Wq, Wih2, bfc1, bq, bih2, bcat2);

    // gvm = vmean @ Wih1[:,1024:3072]^T + bih1  (f32 [128 x 3072])
    CONV(Wih1 + 1024, 4096, nullptr, Wih1m, 3072, 2048);
    mfma_gemm<8, false><<<dim3(24, 1), 256, 0, stream>>>(
        vmeanb, 2048, nullptr, Wih1m, 2048, gvm, 3072, nullptr,
        bih1, nullptr, nullptr, 0, 1, 0, 3072, 2048, 0);

    // gi1s[b*19+t] = emb[cap[b,t]] @ Wih1[:,3072:]^T + gvm[b]
    CONV(emb, 1024, tok_idx, Acap, 2432, 1024);
    mfma_gemm<8, false><<<dim3(24, 19), 256, 0, stream>>>(
        Acap, 1024, nullptr, Wih1c, 1024, gi1s, 3072, nullptr,
        nullptr, nullptr, gvm, 3072, TSTEP, 0, 3072, 1024, 1);

    // ---- recurrent loop: 4 launches/step ----
    for (int t = 0; t < TSTEP; t++) {
        step3_kernel<2, 4><<<dim3(96, 4, 3), 256, 0, stream>>>(
            h1b, h2b, Wih1h, Whh1b, Whh2b, gi, gh, gh2,
            P_gi, P_gh, P_gh2, gi1s + (long)t * 3072, bhh1, bhh2);
        gru_kernel<<<512, 256, 0, stream>>>(gi, P_gi, gh, P_gh, 3, h1, h1b, nullptr, t);
        // [q | gi2_h] = h1' @ Wcat2^T + bcat2 (relu deferred)
        splitk_gemm<2, 4><<<dim3(128, 4), 256, 0, stream>>>(
            h1b, 1024, Wcat2, 1024, qgi2, P_q, 524288, 4096,
            bcat2, nullptr, 0, 4096, 1024);
        attn_gru2_kernel<<<BATCH, 512, 0, stream>>>(
            vw_bf, qgi2, P_q, vwih2, gh2, P_gh2, cap_len, t,
            h2, h2b, H2Ab, alpha);
    }

    // ---- epilogue (Wfc2b conversion deferred: region held vWih2 in loop) ----
    CONV(Wfc2, 1024, nullptr, Wfc2b, NTOKEN, 1024);
    mfma_gemm<8, false><<<dim3(118, 19), 256, 0, stream>>>(
        H2Ab, 1024, nullptr, Wfc2b, 1024, predict, NTOKEN, crow20,
        bfc2, nullptr, nullptr, 0, 1, 0, NTOKEN, 1024, 1);
    softmax_kernel<<<BATCH * MAXLEN, 256, 0, stream>>>(predict, alpha, cap_len);
    #undef CONV
}

// Round 9
// 1924.945 us; speedup vs baseline: 1.4966x; 1.0045x over previous
//
#include <hip/hip_runtime.h>
#include <math.h>

#define NTOKEN 15000
#define EMBED  1024
#define HID    1024
#define VDIM   2048
#define MAXLEN 20
#define BATCH  128
#define NOBJ   36
#define TSTEP  19

typedef unsigned short ushort_t;
typedef __attribute__((ext_vector_type(8))) short short8;
typedef __attribute__((ext_vector_type(4))) float floatx4;

__device__ __forceinline__ float b2f(ushort_t u) {
    return __uint_as_float(((unsigned)u) << 16);
}
__device__ __forceinline__ ushort_t f2b(float f) {
    unsigned x = __float_as_uint(f);
    unsigned r = (x + 0x7fffu + ((x >> 16) & 1u)) >> 16;
    return (ushort_t)r;
}

// async global->LDS, 16B per lane; LDS dest = wave-uniform base + lane*16
__device__ __forceinline__ void gload16(const ushort_t* g, ushort_t* l) {
    __builtin_amdgcn_global_load_lds(
        (const __attribute__((address_space(1))) unsigned int*)g,
        (__attribute__((address_space(3))) unsigned int*)l, 16, 0, 0);
}

// ---------------------------------------------------------------------------
// MFMA bf16 GEMM core, v3: global_load_lds staging (no VGPR staging, no
// ds_write), LDS double-buffer, 1 barrier/k-iter.
// LDS layout: linear [rows][32] ushorts (64 B/row), 16B chunks XOR-swizzled:
// physical chunk c holds global chunk c^(row&3); reads apply the same XOR.
// => conflict-free b128 reads AND linear gload_lds writes (rule 21).
// C[crow?[m]][n] = post( A[arow?[m]][k0:k0+K] @ B^T ), BM=128, BN=NF*16,
// K % 32 == 0. N guarded; crow[m] < 0 -> row write skipped.
// ---------------------------------------------------------------------------
template<int NF, bool OUT_BF16>
__device__ __forceinline__ void mfma_core(
    ushort_t* As, ushort_t* Bs,     // As[2][128*32], Bs[2][NF*16*32]
    const ushort_t* __restrict__ A, int lda, const int* __restrict__ arow,
    const ushort_t* __restrict__ B, int ldb,
    void* __restrict__ Cv, int ldc, const int* __restrict__ crow,
    const float* __restrict__ bias, const float* __restrict__ mulvec,
    const float* __restrict__ cadd, long ldadd, int cadd_div,
    int relu_n, int N, int K, int m0, int n0, int k0)
{
    constexpr int ABUF = 128 * 32;
    constexpr int BBUF = NF * 16 * 32;
    const int tid  = threadIdx.x;
    const int lane = tid & 63;
    const int w    = tid >> 6;

    floatx4 acc[2][NF];
#pragma unroll
    for (int mf = 0; mf < 2; mf++)
#pragma unroll
        for (int nf = 0; nf < NF; nf++) acc[mf][nf] = (floatx4){0.f, 0.f, 0.f, 0.f};

    // staging source coords: wave w, instr j covers rows w*R + j*16 + (lane>>2),
    // chunk (lane&3); source chunk swizzled by ^(row&3).
    const int sr = lane >> 2;
    const int sc = lane & 3;

    int ra0 = w * 32 + sr;
    int ra1 = ra0 + 16;
    int ga0 = m0 + ra0; if (arow) ga0 = arow[ga0];
    int ga1 = m0 + ra1; if (arow) ga1 = arow[ga1];
    const ushort_t* srcA0 = A + (long)ga0 * lda + k0 + ((sc ^ (ra0 & 3)) * 8);
    const ushort_t* srcA1 = A + (long)ga1 * lda + k0 + ((sc ^ (ra1 & 3)) * 8);

    const ushort_t* srcB0;
    const ushort_t* srcB1 = nullptr;
    if constexpr (NF == 8) {
        int rb0 = w * 32 + sr, rb1 = rb0 + 16;
        int gb0 = n0 + rb0; if (gb0 >= N) gb0 = N - 1;
        int gb1 = n0 + rb1; if (gb1 >= N) gb1 = N - 1;
        srcB0 = B + (long)gb0 * ldb + k0 + ((sc ^ (rb0 & 3)) * 8);
        srcB1 = B + (long)gb1 * ldb + k0 + ((sc ^ (rb1 & 3)) * 8);
    } else {
        int rb0 = w * 16 + sr;          // NF=4: waves 0..3; NF=2: waves 0..1
        int gb0 = n0 + rb0; if (gb0 >= N) gb0 = N - 1;
        srcB0 = B + (long)gb0 * ldb + k0 + ((sc ^ (rb0 & 3)) * 8);
    }

    ushort_t* Abase = As + w * 1024;                    // + p*ABUF (+512 for j=1)
    ushort_t* Bbase = (NF == 8) ? (Bs + w * 1024) : (Bs + w * 512);

    auto STAGE = [&](int p, int kk) {
        gload16(srcA0 + kk, Abase + p * ABUF);
        gload16(srcA1 + kk, Abase + p * ABUF + 512);
        if constexpr (NF == 8) {
            gload16(srcB0 + kk, Bbase + p * BBUF);
            gload16(srcB1 + kk, Bbase + p * BBUF + 512);
        } else if constexpr (NF == 4) {
            gload16(srcB0 + kk, Bbase + p * BBUF);
        } else {
            if (w < 2) gload16(srcB0 + kk, Bbase + p * BBUF);
        }
    };

    const int fr   = lane & 15;
    const int aoff = (((lane >> 4) ^ (fr & 3)) * 8);    // swizzled 16B chunk

    auto CMP = [&](const ushort_t* Ap, const ushort_t* Bp) {
        short8 bfr[NF];
#pragma unroll
        for (int nf = 0; nf < NF; nf++)
            bfr[nf] = *(const short8*)(Bp + (nf * 16 + fr) * 32 + aoff);
#pragma unroll
        for (int mf = 0; mf < 2; mf++) {
            short8 af = *(const short8*)(Ap + (w * 32 + mf * 16 + fr) * 32 + aoff);
#pragma unroll
            for (int nf = 0; nf < NF; nf++)
                acc[mf][nf] = __builtin_amdgcn_mfma_f32_16x16x32_bf16(
                    af, bfr[nf], acc[mf][nf], 0, 0, 0);
        }
    };

    const int T = K >> 5;
    STAGE(0, 0);
    __syncthreads();                    // drains vmcnt(0): buf0 ready
    int p = 0;
    for (int i = 0; i < T; i++) {
        if (i + 1 < T) STAGE(p ^ 1, (i + 1) * 32);
        CMP(As + p * ABUF, Bs + p * BBUF);
        __syncthreads();                // all reads of p done; loads into p^1 done
        p ^= 1;
    }

    const int rq = lane >> 4;
#pragma unroll
    for (int mf = 0; mf < 2; mf++) {
#pragma unroll
        for (int r = 0; r < 4; r++) {
            int m = m0 + w * 32 + mf * 16 + rq * 4 + r;
            int cm = crow ? crow[m] : m;
            const float* caddrow = cadd ? (cadd + (long)(m / cadd_div) * ldadd) : nullptr;
#pragma unroll
            for (int nf = 0; nf < NF; nf++) {
                int n = n0 + nf * 16 + fr;
                if (n < N && cm >= 0) {
                    float val = acc[mf][nf][r];
                    if (bias)    val += bias[n];
                    if (caddrow) val += caddrow[n];
                    if (n < relu_n) val = fmaxf(val, 0.f);
                    if (mulvec)  val *= mulvec[n];
                    if (OUT_BF16) ((ushort_t*)Cv)[(long)cm * ldc + n] = f2b(val);
                    else          ((float*)Cv)[(long)cm * ldc + n]   = val;
                }
            }
        }
    }
}

// standalone GEMM; swz!=0 -> XCD-bijective n-slab swizzle (L2 locality).
// crow tiles that are fully dead (crow[m0] < 0; dead rows are a suffix of the
// compacted list) exit before any work.
template<int NF, bool OUT_BF16>
__global__ __launch_bounds__(256) void mfma_gemm(
    const ushort_t* __restrict__ A, int lda, const int* __restrict__ arow,
    const ushort_t* __restrict__ B, int ldb,
    void* __restrict__ C, int ldc, const int* __restrict__ crow,
    const float* __restrict__ bias, const float* __restrict__ mulvec,
    const float* __restrict__ cadd, long ldadd, int cadd_div,
    int relu_n, int N, int K, int swz)
{
    __shared__ ushort_t As[2 * 128 * 32];
    __shared__ ushort_t Bs[2 * NF * 16 * 32];
    int mt = blockIdx.y, nt = blockIdx.x;
    if (swz) {
        int D = gridDim.x * gridDim.y;
        int d = blockIdx.y * gridDim.x + blockIdx.x;   // dispatch-linear id
        int x = d & 7, j = d >> 3, q = D >> 3, r = D & 7;
        int g = x * q + (x < r ? x : r) + j;
        mt = g % gridDim.y; nt = g / gridDim.y;
    }
    if (crow && crow[mt * 128] < 0) return;   // uniform: whole tile dead
    mfma_core<NF, OUT_BF16>(As, Bs, A, lda, arow, B, ldb, C, ldc, crow,
                            bias, mulvec, cadd, ldadd, cadd_div, relu_n,
                            N, K, mt * 128, nt * (NF * 16), 0);
}

// split-K GEMM: blockIdx.y = split s; split 0 -> C0 (+bias/cadd), s>0 -> CP[s-1]
template<int NF, int KS>
__global__ __launch_bounds__(256) void splitk_gemm(
    const ushort_t* __restrict__ A, int lda,
    const ushort_t* __restrict__ B, int ldb,
    float* __restrict__ C0, float* __restrict__ CP, long pstride, int ldc,
    const float* __restrict__ bias,
    const float* __restrict__ cadd, long ldadd,
    int N, int K)
{
    __shared__ ushort_t As[2 * 128 * 32];
    __shared__ ushort_t Bs[2 * NF * 16 * 32];
    const int s = blockIdx.y;
    const int Kc = K / KS;
    float* C = (s == 0) ? C0 : (CP + (long)(s - 1) * pstride);
    mfma_core<NF, false>(As, Bs, A, lda, nullptr, B, ldb, C, ldc, nullptr,
                         s == 0 ? bias : nullptr, nullptr,
                         s == 0 ? cadd : nullptr, ldadd, 1,
                         0, N, Kc, 0, blockIdx.x * (NF * 16), s * Kc);
}

// fused per-step GEMM trio with split-K: z=0 gi1, z=1 gh1, z=2 gh2
template<int NF, int KS>
__global__ __launch_bounds__(256) void step3_kernel(
    const ushort_t* __restrict__ h1b, const ushort_t* __restrict__ h2b,
    const ushort_t* __restrict__ Wih1h, const ushort_t* __restrict__ Whh1b,
    const ushort_t* __restrict__ Whh2b,
    float* __restrict__ gi, float* __restrict__ gh, float* __restrict__ gh2,
    float* __restrict__ P_gi, float* __restrict__ P_gh, float* __restrict__ P_gh2,
    const float* __restrict__ gi1s_t,
    const float* __restrict__ bhh1, const float* __restrict__ bhh2)
{
    __shared__ ushort_t As[2 * 128 * 32];
    __shared__ ushort_t Bs[2 * NF * 16 * 32];
    const int s = blockIdx.y;
    const int Kc = 1024 / KS;
    const ushort_t* A; const ushort_t* B; float* C0; float* CP;
    const float* bias = nullptr; const float* cadd = nullptr;
    if (blockIdx.z == 0)      { A = h2b; B = Wih1h; C0 = gi;  CP = P_gi;  cadd = gi1s_t; }
    else if (blockIdx.z == 1) { A = h1b; B = Whh1b; C0 = gh;  CP = P_gh;  bias = bhh1; }
    else                      { A = h2b; B = Whh2b; C0 = gh2; CP = P_gh2; bias = bhh2; }
    float* C = (s == 0) ? C0 : (CP + (long)(s - 1) * 393216);
    mfma_core<NF, false>(As, Bs, A, 1024, nullptr, B, 1024, C, 3072, nullptr,
                         s == 0 ? bias : nullptr, nullptr,
                         s == 0 ? cadd : nullptr, (long)TSTEP * 3072, 1, 0,
                         3072, Kc, 0, blockIdx.x * (NF * 16), s * Kc);
}

// ---------------------------------------------------------------------------
// small helper kernels
// ---------------------------------------------------------------------------
__global__ void init_kernel(const int* __restrict__ caption,
                            int* __restrict__ tok_idx,
                            float* __restrict__ h12f, ushort_t* __restrict__ h12b)
{
    int idx = blockIdx.x * 256 + threadIdx.x;   // 262144 threads
    if (idx < BATCH * TSTEP) {
        int b = idx / TSTEP, t = idx % TSTEP;
        tok_idx[idx] = caption[b * MAXLEN + t];
    }
    h12f[idx] = 0.f;
    h12b[idx] = 0;
}

// sort_caption for out1 + build compacted live-row lists for the epilogue:
// arow2[i] = H2Ab row (b*19+t), crow2[i] = predict row (b*20+t) for live
// (t < cap_len[b]-1) pairs, packed; padding arow2=0, crow2=-1.
__global__ void sort_caption_kernel(const int* __restrict__ caption,
                                    const int* __restrict__ cap_len,
                                    float* __restrict__ out1,
                                    int* __restrict__ arow2,
                                    int* __restrict__ crow2)
{
    __shared__ int s_dec[BATCH];
    __shared__ int ofs[BATCH + 1];
    int i = threadIdx.x;
    int li = cap_len[i];
    int dec = li - 1;
    // stable descending-length rank for out1
    int rank = 0;
    for (int j = 0; j < BATCH; j++) {
        int lj = cap_len[j];
        if (lj > li || (lj == li && j < i)) rank++;
    }
    for (int k = 0; k < TSTEP; k++)
        out1[rank * TSTEP + k] = (float)caption[i * MAXLEN + 1 + k];
    // compaction scan
    s_dec[i] = dec;
    __syncthreads();
    if (i == 0) {
        int acc = 0;
        for (int b = 0; b < BATCH; b++) { ofs[b] = acc; acc += s_dec[b]; }
        ofs[BATCH] = acc;
    }
    __syncthreads();
    int off = ofs[i];
    for (int k = 0; k < dec; k++) {
        arow2[off + k] = i * TSTEP + k;
        crow2[off + k] = i * MAXLEN + k;
    }
    int total = ofs[BATCH];
    for (int idx = total + i; idx < BATCH * TSTEP; idx += BATCH) {
        arow2[idx] = 0;
        crow2[idx] = -1;
    }
}

__global__ void vmean_kernel(const float* __restrict__ v,
                             float* __restrict__ vmean, ushort_t* __restrict__ vmeanb)
{
    int idx = blockIdx.x * 256 + threadIdx.x;   // BATCH*VDIM
    int b = idx >> 11, d = idx & (VDIM - 1);
    float s = 0.f;
    for (int o = 0; o < NOBJ; o++) s += v[((long)b * NOBJ + o) * VDIM + d];
    float m = s * (1.0f / 36.0f);
    vmean[idx] = m;
    vmeanb[idx] = f2b(m);
}

// strided (optionally row-gathered) f32 -> bf16 convert, 4 elems/thread
__global__ void conv_kernel(const float* __restrict__ src, long ld,
                            const int* __restrict__ rowidx,
                            ushort_t* __restrict__ dst, int rows, int cols)
{
    long idx4 = ((long)blockIdx.x * 256 + threadIdx.x) * 4;
    if (idx4 >= (long)rows * cols) return;
    int r = (int)(idx4 / cols);
    int c = (int)(idx4 % cols);
    long sr = rowidx ? rowidx[r] : r;
    float4 f = *(const float4*)(src + sr * ld + c);
    dst[idx4 + 0] = f2b(f.x);
    dst[idx4 + 1] = f2b(f.y);
    dst[idx4 + 2] = f2b(f.z);
    dst[idx4 + 3] = f2b(f.w);
}

// Wfc1 [1024x1024] -> Wfc1T bf16 (dst[n*1024+k] = src[k*1024+n])
__global__ void transpose_conv_kernel(const float* __restrict__ src,
                                      ushort_t* __restrict__ dst)
{
    __shared__ float tile[32][33];
    int bx = blockIdx.x, by = blockIdx.y;
    int lx = threadIdx.x & 31, ly = threadIdx.x >> 5;   // ly 0..7
    for (int i = 0; i < 32; i += 8)
        tile[ly + i][lx] = src[(long)(by * 32 + ly + i) * 1024 + bx * 32 + lx];
    __syncthreads();
    for (int i = 0; i < 32; i += 8)
        dst[(long)(bx * 32 + ly + i) * 1024 + by * 32 + lx] = f2b(tile[lx][ly + i]);
}

// bcat2[0:1024] = bq + Wq @ bfc1 ; bcat2[1024:4096] = bih2 + Wih2[:,2048:] @ bfc1
__global__ void bias_fold_kernel(const float* __restrict__ Wq,
                                 const float* __restrict__ Wih2,
                                 const float* __restrict__ bfc1,
                                 const float* __restrict__ bq,
                                 const float* __restrict__ bih2,
                                 float* __restrict__ bcat2)
{
    int wave = blockIdx.x * 4 + (threadIdx.x >> 6);
    int lane = threadIdx.x & 63;
    for (int n = wave; n < 4096; n += 256) {
        const float* wrow = (n < 1024) ? (Wq + (long)n * 1024)
                                       : (Wih2 + (long)(n - 1024) * 3072 + 2048);
        float s = 0.f;
        for (int j = lane; j < 1024; j += 64) s += wrow[j] * bfc1[j];
        for (int off = 32; off > 0; off >>= 1) s += __shfl_down(s, off);
        if (lane == 0) bcat2[n] = s + ((n < 1024) ? bq[n] : bih2[n - 1024]);
    }
}

// GRU combine (gru1): gate = gi + sum_s giP[s] ; same for gh
__global__ void gru_kernel(const float* __restrict__ gi, const float* __restrict__ giP,
                           const float* __restrict__ gh, const float* __restrict__ ghP,
                           int nsp,
                           float* __restrict__ h, ushort_t* __restrict__ hb,
                           ushort_t* __restrict__ hstore, int t)
{
    int idx = blockIdx.x * 256 + threadIdx.x;   // BATCH*HID
    int b = idx >> 10, j = idx & (HID - 1);
    long o0 = (long)b * 3 * HID + j;
    float ir = gi[o0], iz = gi[o0 + HID], in_ = gi[o0 + 2 * HID];
    float hr = gh[o0], hz = gh[o0 + HID], hn  = gh[o0 + 2 * HID];
    for (int s = 0; s < nsp; s++) {
        const float* gp = giP + (long)s * 393216;
        const float* hp = ghP + (long)s * 393216;
        ir  += gp[o0]; iz += gp[o0 + HID]; in_ += gp[o0 + 2 * HID];
        hr  += hp[o0]; hz += hp[o0 + HID]; hn  += hp[o0 + 2 * HID];
    }
    float r = 1.f / (1.f + expf(-(ir + hr)));
    float z = 1.f / (1.f + expf(-(iz + hz)));
    float n = tanhf(in_ + r * hn);
    float hnew = (1.f - z) * n + z * h[idx];
    h[idx] = hnew;
    ushort_t hq = f2b(hnew);
    hb[idx] = hq;
    if (hstore) hstore[((long)(b * TSTEP + t) << 10) | j] = hq;
}

// fused attention + gi2 (via precomputed vWih2) + gru2, v2.
// grid (BATCH, 4): block (b, y) redundantly computes q/att/softmax (cheap),
// then owns j-slice [y*256, (y+1)*256) of the heavy gi2+gru2 phase.
__global__ __launch_bounds__(256) void attn_gru2_kernel(
    const ushort_t* __restrict__ vwb, const float* __restrict__ qgi2,
    const float* __restrict__ qP,
    const ushort_t* __restrict__ vwih2,   // [B*NOBJ*3072] bf16
    const float* __restrict__ gh2, const float* __restrict__ ghP2,
    const int* __restrict__ cap_len, int t,
    float* __restrict__ h2, ushort_t* __restrict__ h2b,
    ushort_t* __restrict__ hstore, float* __restrict__ alpha)
{
    int b = blockIdx.x, y = blockIdx.y;
    __shared__ float qs[HID];
    __shared__ float att_s[NOBJ];
    int tid = threadIdx.x, lane = tid & 63, w = tid >> 6;   // 4 waves
    const float* qb = qgi2 + (long)b * 4096;

    // q = relu(sum of 4 partials)
    for (int hh = tid; hh < HID; hh += 256) {
        float s = qb[hh];
        for (int sp = 0; sp < 3; sp++) s += qP[(long)sp * 524288 + (long)b * 4096 + hh];
        qs[hh] = fmaxf(s, 0.f);
    }
    __syncthreads();

    for (int o = w; o < NOBJ; o += 4) {
        const ushort_t* vwo = vwb + ((long)b * NOBJ + o) * HID;
        float s = 0.f;
        for (int hh = lane * 8; hh < HID; hh += 512) {   // 2 iters, short8 loads
            short8 v8 = *(const short8*)(vwo + hh);
#pragma unroll
            for (int k = 0; k < 8; k++) s += b2f((ushort_t)v8[k]) * qs[hh + k];
        }
        for (int off = 32; off > 0; off >>= 1) s += __shfl_down(s, off);
        if (lane == 0) att_s[o] = s;
    }
    __syncthreads();
    if (tid == 0) {
        float mx = att_s[0];
        for (int o = 1; o < NOBJ; o++) mx = fmaxf(mx, att_s[o]);
        float sum = 0.f;
        for (int o = 0; o < NOBJ; o++) { float e = expf(att_s[o] - mx); att_s[o] = e; sum += e; }
        float inv = 1.f / sum;
        for (int o = 0; o < NOBJ; o++) att_s[o] *= inv;
    }
    __syncthreads();
    bool m = (t < cap_len[b] - 1);
    if (y == 0 && tid < NOBJ)
        alpha[((long)b * MAXLEN + t) * NOBJ + tid] = m ? att_s[tid] : 0.f;

    // gi2 + gru2 for this block's j-slice (one j per thread)
    int j = y * 256 + tid;
    long qoff = (long)b * 4096 + HID + j;
    float ir = qgi2[qoff], iz = qgi2[qoff + 1024], in_ = qgi2[qoff + 2048];
    for (int sp = 0; sp < 3; sp++) {
        const float* qpp = qP + (long)sp * 524288;
        ir += qpp[qoff]; iz += qpp[qoff + 1024]; in_ += qpp[qoff + 2048];
    }
    const ushort_t* vw2 = vwih2 + (long)b * NOBJ * 3072 + j;
    for (int o = 0; o < NOBJ; o++) {
        float a = att_s[o];
        const ushort_t* p = vw2 + (long)o * 3072;
        ir  += a * b2f(p[0]);
        iz  += a * b2f(p[1024]);
        in_ += a * b2f(p[2048]);
    }
    long o0 = (long)b * 3 * HID + j;
    float hr = gh2[o0], hz = gh2[o0 + HID], hn = gh2[o0 + 2 * HID];
    for (int sp = 0; sp < 3; sp++) {
        const float* hp = ghP2 + (long)sp * 393216;
        hr += hp[o0]; hz += hp[o0 + HID]; hn += hp[o0 + 2 * HID];
    }
    float r = 1.f / (1.f + expf(-(ir + hr)));
    float z = 1.f / (1.f + expf(-(iz + hz)));
    float n = tanhf(in_ + r * hn);
    int idx = (b << 10) | j;
    float hnew = (1.f - z) * n + z * h2[idx];
    h2[idx] = hnew;
    ushort_t hq = f2b(hnew);
    h2b[idx] = hq;
    hstore[((long)(b * TSTEP + t) << 10) | j] = hq;
}

// row softmax over NTOKEN, single global read via LDS staging
__global__ __launch_bounds__(256) void softmax_kernel(float* __restrict__ predict,
                                                      float* __restrict__ alpha,
                                                      const int* __restrict__ cap_len)
{
    __shared__ float ls[NTOKEN];     // 60000 B
    __shared__ float sred[4];
    int row = blockIdx.x;                 // b*20 + t
    int b = row / MAXLEN, t = row % MAXLEN;
    float* p = predict + (long)row * NTOKEN;
    int tid = threadIdx.x;
    int dec = cap_len[b] - 1;
    if (t >= dec) {
        const float u = 1.0f / (float)NTOKEN;
        for (int i = tid; i < NTOKEN; i += 256) p[i] = u;
        if (t == MAXLEN - 1 && tid < NOBJ) alpha[(long)row * NOBJ + tid] = 0.f;
        return;
    }
    float mx = -3.4e38f;
    for (int i = tid; i < NTOKEN; i += 256) {
        float x = p[i]; ls[i] = x; mx = fmaxf(mx, x);
    }
    for (int off = 32; off > 0; off >>= 1) mx = fmaxf(mx, __shfl_down(mx, off));
    if ((tid & 63) == 0) sred[tid >> 6] = mx;
    __syncthreads();
    mx = fmaxf(fmaxf(sred[0], sred[1]), fmaxf(sred[2], sred[3]));
    __syncthreads();
    float s = 0.f;
    for (int i = tid; i < NTOKEN; i += 256) {
        float e = expf(ls[i] - mx); ls[i] = e; s += e;
    }
    for (int off = 32; off > 0; off >>= 1) s += __shfl_down(s, off);
    if ((tid & 63) == 0) sred[tid >> 6] = s;
    __syncthreads();
    s = sred[0] + sred[1] + sred[2] + sred[3];
    float inv = 1.f / s;
    for (int i = tid; i < NTOKEN; i += 256) p[i] = ls[i] * inv;
}

// ---------------------------------------------------------------------------
extern "C" void kernel_launch(void* const* d_in, const int* in_sizes, int n_in,
                              void* d_out, int out_size, void* d_ws, size_t ws_size,
                              hipStream_t stream)
{
    const float* v       = (const float*)d_in[0];
    const int*   caption = (const int*)  d_in[1];
    const int*   cap_len = (const int*)  d_in[2];
    const float* emb     = (const float*)d_in[3];
    const float* Wih1    = (const float*)d_in[4];
    const float* Whh1    = (const float*)d_in[5];
    const float* bih1    = (const float*)d_in[6];
    const float* bhh1    = (const float*)d_in[7];
    const float* Wih2    = (const float*)d_in[8];
    const float* Whh2    = (const float*)d_in[9];
    const float* bih2    = (const float*)d_in[10];
    const float* bhh2    = (const float*)d_in[11];
    const float* Wfc1    = (const float*)d_in[12];
    const float* bfc1    = (const float*)d_in[13];
    const float* Wfc2    = (const float*)d_in[14];
    const float* bfc2    = (const float*)d_in[15];
    const float* Wv      = (const float*)d_in[16];
    const float* bv      = (const float*)d_in[17];
    const float* Wq      = (const float*)d_in[18];
    const float* bq      = (const float*)d_in[19];
    const float* Wa      = (const float*)d_in[20];
    // ba cancels in softmax

    // ---- workspace layout ----
    float* f32base = (float*)d_ws;
    float* gvm   = f32base;              // 128*3072
    float* gi1s  = gvm   + 393216;       // 2432*3072
    float* h1    = gi1s  + 7471104;      // 128*1024  (h1,h2 contiguous)
    float* h2    = h1    + 131072;
    float* gi    = h2    + 131072;       // 128*3072
    float* gh    = gi    + 393216;
    float* gh2   = gh    + 393216;
    float* qgi2  = gh2   + 393216;       // 128*4096
    float* vmean = qgi2  + 524288;       // 128*2048
    float* bcat2 = vmean + 262144;       // 4096
    ushort_t* ub = (ushort_t*)(bcat2 + 4096);
    ushort_t* Wih1h = ub;                 // 3072*1024
    ushort_t* Wih1c = Wih1h + 3145728;    // 3072*1024
    ushort_t* Whh1b = Wih1c + 3145728;    // 3072*1024
    ushort_t* Whh2b = Whh1b + 3145728;    // 3072*1024
    ushort_t* Wih2v = Whh2b + 3145728;    // 3072*2048
    ushort_t* Wcat2 = Wih2v + 6291456;    // 4096*1024
    ushort_t* Wfc2b = Wcat2 + 4194304;    // 15000*1024 (epilogue) / vwih2 (loop)
    ushort_t* vw_bf = Wfc2b + 15360000;   // 4608*1024
    ushort_t* H2Ab  = vw_bf + 4718592;    // 2432*1024
    ushort_t* h1b   = H2Ab  + 2490368;    // 128*1024 (h1b,h2b contiguous)
    ushort_t* h2b   = h1b   + 131072;
    ushort_t* x2v   = h2b   + 131072;     // 128*2048 (unused, layout kept)
    ushort_t* vmeanb= x2v   + 262144;     // 128*2048
    ushort_t* TEMP  = vmeanb+ 262144;     // 11534336 max
    // vwih2 aliases the Wfc2b region (dead until post-loop): 128*36*3072 = 14155776
    ushort_t* vwih2 = Wfc2b;
    // TEMP sub-uses — prologue scratch (sequential in stream):
    ushort_t* vb     = TEMP;              // 4608*2048
    ushort_t* Wvb    = TEMP + 9437184;    // 1024*2048
    ushort_t* Wqb    = TEMP;              // 1024*1024
    ushort_t* Wih2hb = TEMP + 1048576;    // 3072*1024
    ushort_t* Wfc1T  = TEMP + 4194304;    // 1024*1024
    ushort_t* Wih1m  = TEMP;              // 3072*2048
    ushort_t* Acap   = TEMP;              // 2432*1024
    // TEMP sub-uses — recurrent-loop split-K partials:
    float* TEMPf  = (float*)TEMP;         // 5767168 floats capacity
    float* P_gi   = TEMPf;                // 3 * 393216
    float* P_gh   = P_gi  + 3 * 393216;   // 3 * 393216
    float* P_gh2  = P_gh  + 3 * 393216;   // 3 * 393216
    float* P_q    = P_gh2 + 3 * 393216;   // 3 * 524288  (total 5111808 < 5767168)
    int* tok_idx = (int*)(TEMP + 11534336);
    int* arow2   = tok_idx + BATCH * TSTEP;   // 2432 (compacted H2Ab rows)
    int* crow2   = arow2   + BATCH * TSTEP;   // 2432 (compacted predict rows)

    float* out     = (float*)d_out;
    float* predict = out;                                   // 128*20*15000
    float* out1    = out + (long)BATCH * MAXLEN * NTOKEN;   // 128*19
    float* alpha   = out1 + (long)BATCH * TSTEP;            // 128*20*36

    #define CONV(src, ld, rowidx, dst, rows, cols) \
        conv_kernel<<<(int)(((long)(rows)*(cols)/4 + 255)/256), 256, 0, stream>>>( \
            src, ld, rowidx, dst, rows, cols)

    // ---- prologue ----
    init_kernel<<<1024, 256, 0, stream>>>(caption, tok_idx, h1, h1b);
    sort_caption_kernel<<<1, 128, 0, stream>>>(caption, cap_len, out1, arow2, crow2);
    vmean_kernel<<<(BATCH * VDIM) / 256, 256, 0, stream>>>(v, vmean, vmeanb);

    CONV(Wih1,        4096, nullptr, Wih1h, 3072, 1024);
    CONV(Wih1 + 3072, 4096, nullptr, Wih1c, 3072, 1024);
    CONV(Whh1,        1024, nullptr, Whh1b, 3072, 1024);
    CONV(Whh2,        1024, nullptr, Whh2b, 3072, 1024);
    CONV(Wih2,        3072, nullptr, Wih2v, 3072, 2048);

    // vw = relu(v @ Wv^T + bv) * Wa  -> bf16 [4608 x 1024]
    CONV(v,  2048, nullptr, vb,  4608, 2048);
    CONV(Wv, 2048, nullptr, Wvb, 1024, 2048);
    mfma_gemm<8, true><<<dim3(8, 36), 256, 0, stream>>>(
        vb, 2048, nullptr, Wvb, 2048, vw_bf, 1024, nullptr,
        bv, Wa, nullptr, 0, 1, 1024, 1024, 2048, 1);

    // vWih2[b,o,:] = v[b,o,:] @ Wih2[:, :2048]^T  -> bf16 [4608 x 3072]
    mfma_gemm<8, true><<<dim3(24, 36), 256, 0, stream>>>(
        vb, 2048, nullptr, Wih2v, 2048, vwih2, 3072, nullptr,
        nullptr, nullptr, nullptr, 0, 1, 0, 3072, 2048, 1);

    // folded weights: Wcat2 = [Wq@Wfc1 ; Wih2[:,2048:]@Wfc1]
    CONV(Wq,          1024, nullptr, Wqb,    1024, 1024);
    CONV(Wih2 + 2048, 3072, nullptr, Wih2hb, 3072, 1024);
    transpose_conv_kernel<<<dim3(32, 32), 256, 0, stream>>>(Wfc1, Wfc1T);
    mfma_gemm<8, true><<<dim3(8, 8), 256, 0, stream>>>(
        Wqb, 1024, nullptr, Wfc1T, 1024, Wcat2, 1024, nullptr,
        nullptr, nullptr, nullptr, 0, 1, 0, 1024, 1024, 1);
    mfma_gemm<8, true><<<dim3(8, 24), 256, 0, stream>>>(
        Wih2hb, 1024, nullptr, Wfc1T, 1024, Wcat2 + 1048576, 1024, nullptr,
        nullptr, nullptr, nullptr, 0, 1, 0, 1024, 1024, 1);
    bias_fold_kernel<<<64, 256, 0, stream>>>(Wq, Wih2, bfc1, bq, bih2, bcat2);

    // gvm = vmean @ Wih1[:,1024:3072]^T + bih1  (f32 [128 x 3072])
    CONV(Wih1 + 1024, 4096, nullptr, Wih1m, 3072, 2048);
    mfma_gemm<8, false><<<dim3(24, 1), 256, 0, stream>>>(
        vmeanb, 2048, nullptr, Wih1m, 2048, gvm, 3072, nullptr,
        bih1, nullptr, nullptr, 0, 1, 0, 3072, 2048, 0);

    // gi1s[b*19+t] = emb[cap[b,t]] @ Wih1[:,3072:]^T + gvm[b]
    CONV(emb, 1024, tok_idx, Acap, 2432, 1024);
    mfma_gemm<8, false><<<dim3(24, 19), 256, 0, stream>>>(
        Acap, 1024, nullptr, Wih1c, 1024, gi1s, 3072, nullptr,
        nullptr, nullptr, gvm, 3072, TSTEP, 0, 3072, 1024, 1);

    // ---- recurrent loop: 4 launches/step ----
    for (int t = 0; t < TSTEP; t++) {
        step3_kernel<2, 4><<<dim3(96, 4, 3), 256, 0, stream>>>(
            h1b, h2b, Wih1h, Whh1b, Whh2b, gi, gh, gh2,
            P_gi, P_gh, P_gh2, gi1s + (long)t * 3072, bhh1, bhh2);
        gru_kernel<<<512, 256, 0, stream>>>(gi, P_gi, gh, P_gh, 3, h1, h1b, nullptr, t);
        // [q | gi2_h] = h1' @ Wcat2^T + bcat2 (relu deferred)
        splitk_gemm<2, 4><<<dim3(128, 4), 256, 0, stream>>>(
            h1b, 1024, Wcat2, 1024, qgi2, P_q, 524288, 4096,
            bcat2, nullptr, 0, 4096, 1024);
        attn_gru2_kernel<<<dim3(BATCH, 4), 256, 0, stream>>>(
            vw_bf, qgi2, P_q, vwih2, gh2, P_gh2, cap_len, t,
            h2, h2b, H2Ab, alpha);
    }

    // ---- epilogue: compacted live rows only (dead rows -> softmax uniform) ----
    CONV(Wfc2, 1024, nullptr, Wfc2b, NTOKEN, 1024);
    mfma_gemm<8, false><<<dim3(118, 19), 256, 0, stream>>>(
        H2Ab, 1024, arow2, Wfc2b, 1024, predict, NTOKEN, crow2,
        bfc2, nullptr, nullptr, 0, 1, 0, NTOKEN, 1024, 1);
    softmax_kernel<<<BATCH * MAXLEN, 256, 0, stream>>>(predict, alpha, cap_len);
    #undef CONV
}